// Round 1
// baseline (4335.236 us; speedup 1.0000x reference)
//
#include <hip/hip_runtime.h>
#include <hip/hip_bf16.h>
#include <stdint.h>

#define NH 8
#define DH 16

// ---------- helpers ----------
__device__ __forceinline__ unsigned short f2bf(float x) {
    unsigned u = __float_as_uint(x);
    u += 0x7fffu + ((u >> 16) & 1u);   // round-to-nearest-even
    return (unsigned short)(u >> 16);
}

__device__ __forceinline__ void atomAddF(float* p, float v) {
    unsafeAtomicAdd(p, v);   // native global_atomic_add_f32 on gfx950
}

// load 16 bf16 (32B, aligned) -> 16 floats
__device__ __forceinline__ void load16bf(const unsigned short* p, float* f) {
    uint4 a = *reinterpret_cast<const uint4*>(p);
    uint4 b = *reinterpret_cast<const uint4*>(p + 8);
    unsigned u[8] = {a.x, a.y, a.z, a.w, b.x, b.y, b.z, b.w};
#pragma unroll
    for (int i = 0; i < 8; ++i) {
        f[2 * i]     = __uint_as_float(u[i] << 16);
        f[2 * i + 1] = __uint_as_float(u[i] & 0xffff0000u);
    }
}

// ---------- GEMM: C[M,128] = A[M,K] @ W[K,128] + bias ----------
// MODE 0: store bf16 ; MODE 1: store f32 ; MODE 2: accumulate into f32
template <int K, int MODE>
__global__ __launch_bounds__(256) void gemm_n128(const float* __restrict__ A,
                                                 const float* __restrict__ W,
                                                 const float* __restrict__ bias,
                                                 void* __restrict__ Cv, int M) {
    __shared__ __align__(16) float As[16 * 68];   // [kk][row], padded stride 68
    __shared__ __align__(16) float Ws[16 * 128];  // [kk][col]

    const int tid = threadIdx.x;
    const int tx = tid & 31;        // col group: cols tx*4 .. tx*4+3
    const int ty = tid >> 5;        // row group: rows ty*8 .. ty*8+7
    const int rowBase = blockIdx.x * 64;

    float acc[8][4];
#pragma unroll
    for (int j = 0; j < 8; ++j)
#pragma unroll
        for (int c = 0; c < 4; ++c) acc[j][c] = 0.f;

    const int arow = tid >> 2, aj = tid & 3;

    for (int kb = 0; kb < K; kb += 16) {
        // stage A chunk (64 rows x 16 k) transposed into LDS
        float4 a4 = make_float4(0.f, 0.f, 0.f, 0.f);
        int gr = rowBase + arow;
        if (gr < M)
            a4 = *reinterpret_cast<const float4*>(&A[(size_t)gr * K + kb + aj * 4]);
        As[(aj * 4 + 0) * 68 + arow] = a4.x;
        As[(aj * 4 + 1) * 68 + arow] = a4.y;
        As[(aj * 4 + 2) * 68 + arow] = a4.z;
        As[(aj * 4 + 3) * 68 + arow] = a4.w;
        // stage W chunk (16 x 128)
#pragma unroll
        for (int f = tid; f < 512; f += 256) {
            int kk = f >> 5, c4 = f & 31;
            *reinterpret_cast<float4*>(&Ws[kk * 128 + c4 * 4]) =
                *reinterpret_cast<const float4*>(&W[(size_t)(kb + kk) * 128 + c4 * 4]);
        }
        __syncthreads();
#pragma unroll
        for (int kk = 0; kk < 16; ++kk) {
            float4 wv = *reinterpret_cast<const float4*>(&Ws[kk * 128 + tx * 4]);
            float4 a0 = *reinterpret_cast<const float4*>(&As[kk * 68 + ty * 8]);
            float4 a1 = *reinterpret_cast<const float4*>(&As[kk * 68 + ty * 8 + 4]);
            float av[8] = {a0.x, a0.y, a0.z, a0.w, a1.x, a1.y, a1.z, a1.w};
#pragma unroll
            for (int j = 0; j < 8; ++j) {
                acc[j][0] += av[j] * wv.x;
                acc[j][1] += av[j] * wv.y;
                acc[j][2] += av[j] * wv.z;
                acc[j][3] += av[j] * wv.w;
            }
        }
        __syncthreads();
    }

    float4 bv = *reinterpret_cast<const float4*>(&bias[tx * 4]);
#pragma unroll
    for (int j = 0; j < 8; ++j) {
        int r = rowBase + ty * 8 + j;
        if (r >= M) continue;
        float o0 = acc[j][0] + bv.x, o1 = acc[j][1] + bv.y;
        float o2 = acc[j][2] + bv.z, o3 = acc[j][3] + bv.w;
        if (MODE == 0) {
            unsigned short* C = (unsigned short*)Cv;
            uint2 pk;
            pk.x = (unsigned)f2bf(o0) | ((unsigned)f2bf(o1) << 16);
            pk.y = (unsigned)f2bf(o2) | ((unsigned)f2bf(o3) << 16);
            *reinterpret_cast<uint2*>(&C[(size_t)r * 128 + tx * 4]) = pk;
        } else if (MODE == 1) {
            float* C = (float*)Cv;
            *reinterpret_cast<float4*>(&C[(size_t)r * 128 + tx * 4]) =
                make_float4(o0, o1, o2, o3);
        } else {
            float* C = (float*)Cv;
            float4 pr = *reinterpret_cast<float4*>(&C[(size_t)r * 128 + tx * 4]);
            *reinterpret_cast<float4*>(&C[(size_t)r * 128 + tx * 4]) =
                make_float4(pr.x + o0, pr.y + o1, pr.z + o2, pr.w + o3);
        }
    }
}

// ---------- edge attention: one thread per (edge, head) ----------
// s = scale * q[dst,h]·(k[src,h]+e[edge,h]);  ex = exp(s)  (|s| << 1, no max needed)
// den[dst,h] += ex;  agg[dst,h,:] += ex*(v[src,h,:]+e[edge,h,:])
__global__ __launch_bounds__(256) void edge_attn(const unsigned short* __restrict__ q,
                                                 const unsigned short* __restrict__ k,
                                                 const unsigned short* __restrict__ v,
                                                 const unsigned short* __restrict__ e,
                                                 const int* __restrict__ ei,
                                                 float* __restrict__ den,
                                                 float* __restrict__ agg, int E) {
    int t = blockIdx.x * 256 + threadIdx.x;
    if (t >= E * NH) return;
    int edge = t >> 3, h = t & 7;
    int src = ei[edge];
    int dst = ei[E + edge];

    float qf[16], kf[16], vf[16], ef[16];
    load16bf(q + (size_t)dst * 128 + h * 16, qf);
    load16bf(k + (size_t)src * 128 + h * 16, kf);
    load16bf(v + (size_t)src * 128 + h * 16, vf);
    load16bf(e + (size_t)edge * 128 + h * 16, ef);

    float s = 0.f;
#pragma unroll
    for (int d = 0; d < 16; ++d) s += qf[d] * (kf[d] + ef[d]);
    float ex = __expf(s * 0.25f);  // scale = 16^-0.5

    atomAddF(&den[(size_t)dst * NH + h], ex);
    float* ap = agg + (size_t)dst * 128 + h * 16;
#pragma unroll
    for (int d = 0; d < 16; ++d) atomAddF(&ap[d], ex * (vf[d] + ef[d]));
}

// ---------- normalize agg by den (guard zero-degree nodes) ----------
__global__ __launch_bounds__(256) void norm_agg(float* __restrict__ agg,
                                                const float* __restrict__ den, int N) {
    int idx = blockIdx.x * 256 + threadIdx.x;
    if (idx >= N * 128) return;
    int n = idx >> 7, h = (idx >> 4) & 7;
    float dd = den[n * NH + h];
    float val = agg[idx];
    agg[idx] = dd > 0.f ? val / dd : 0.f;
}

// ---------- layernorm over 128 cols, one wave per row ----------
__global__ __launch_bounds__(256) void layernorm128(float* __restrict__ out,
                                                    const float* __restrict__ g,
                                                    const float* __restrict__ b, int N) {
    int row = blockIdx.x * 4 + (threadIdx.x >> 6);
    int lane = threadIdx.x & 63;
    if (row >= N) return;
    float* p = out + (size_t)row * 128;
    float x0 = p[lane], x1 = p[lane + 64];
    float sum = x0 + x1;
#pragma unroll
    for (int off = 1; off < 64; off <<= 1) sum += __shfl_xor(sum, off, 64);
    float mu = sum * (1.f / 128.f);
    float d0 = x0 - mu, d1 = x1 - mu;
    float vs = d0 * d0 + d1 * d1;
#pragma unroll
    for (int off = 1; off < 64; off <<= 1) vs += __shfl_xor(vs, off, 64);
    float r = rsqrtf(vs * (1.f / 128.f) + 1e-5f);
    p[lane]      = d0 * r * g[lane] + b[lane];
    p[lane + 64] = d1 * r * g[lane + 64] + b[lane + 64];
}

extern "C" void kernel_launch(void* const* d_in, const int* in_sizes, int n_in,
                              void* d_out, int out_size, void* d_ws, size_t ws_size,
                              hipStream_t stream) {
    const float* x_pc  = (const float*)d_in[0];
    const float* x_gr  = (const float*)d_in[1];
    const float* ea_pp = (const float*)d_in[2];
    const float* ea_pg = (const float*)d_in[3];
    const int* ei_pp   = (const int*)d_in[4];
    const int* ei_pg   = (const int*)d_in[5];
    const float *Wq_pp = (const float*)d_in[6],  *bq_pp = (const float*)d_in[7];
    const float *Wk_pp = (const float*)d_in[8],  *bk_pp = (const float*)d_in[9];
    const float *Wv_pp = (const float*)d_in[10], *bv_pp = (const float*)d_in[11];
    const float *We_pp = (const float*)d_in[12], *be_pp = (const float*)d_in[13];
    const float *Wo_pp = (const float*)d_in[14], *bo_pp = (const float*)d_in[15];
    const float *Wq_pg = (const float*)d_in[16], *bq_pg = (const float*)d_in[17];
    const float *Wk_pg = (const float*)d_in[18], *bk_pg = (const float*)d_in[19];
    const float *Wv_pg = (const float*)d_in[20], *bv_pg = (const float*)d_in[21];
    const float *We_pg = (const float*)d_in[22], *be_pg = (const float*)d_in[23];
    const float *Wo_pg = (const float*)d_in[24], *bo_pg = (const float*)d_in[25];
    const float *Wnp_pc = (const float*)d_in[26], *bnp_pc = (const float*)d_in[27];
    const float *g_pc   = (const float*)d_in[28], *bln_pc = (const float*)d_in[29];
    const float *Wnp_gr = (const float*)d_in[30], *bnp_gr = (const float*)d_in[31];
    const float *g_gr   = (const float*)d_in[32], *bln_gr = (const float*)d_in[33];

    const int N_pc = in_sizes[0] / 128;
    const int N_gr = in_sizes[1] / 128;
    const int E_pp = in_sizes[4] / 2;
    const int E_pg = in_sizes[5] / 2;

    char* ws = (char*)d_ws;
    size_t off = 0;
    auto alloc = [&](size_t bytes) -> char* {
        char* p = ws + off;
        off += (bytes + 255) & ~(size_t)255;
        return p;
    };
    unsigned short* q_pp = (unsigned short*)alloc((size_t)N_pc * 128 * 2);
    unsigned short* k_pp = (unsigned short*)alloc((size_t)N_pc * 128 * 2);
    unsigned short* v_pp = (unsigned short*)alloc((size_t)N_pc * 128 * 2);
    unsigned short* e_pp = (unsigned short*)alloc((size_t)E_pp * 128 * 2);
    unsigned short* q_pg = (unsigned short*)alloc((size_t)N_gr * 128 * 2);
    unsigned short* k_pg = (unsigned short*)alloc((size_t)N_pc * 128 * 2);
    unsigned short* v_pg = (unsigned short*)alloc((size_t)N_pc * 128 * 2);
    unsigned short* e_pg = (unsigned short*)alloc((size_t)E_pg * 128 * 2);
    char* zbase = ws + off;  // contiguous zero-init region
    float* den_pp = (float*)alloc((size_t)N_pc * NH * 4);
    float* agg_pp = (float*)alloc((size_t)N_pc * 128 * 4);
    float* den_pg = (float*)alloc((size_t)N_gr * NH * 4);
    float* agg_pg = (float*)alloc((size_t)N_gr * 128 * 4);
    size_t zbytes = (size_t)((ws + off) - zbase);
    hipMemsetAsync(zbase, 0, zbytes, stream);

    float* out_pc = (float*)d_out;
    float* out_gr = out_pc + (size_t)N_pc * 128;

    auto b64 = [](int M) { return (M + 63) / 64; };

    // ---- pp (pc -> pc) ----
    gemm_n128<128, 0><<<b64(N_pc), 256, 0, stream>>>(x_pc, Wq_pp, bq_pp, q_pp, N_pc);
    gemm_n128<128, 0><<<b64(N_pc), 256, 0, stream>>>(x_pc, Wk_pp, bk_pp, k_pp, N_pc);
    gemm_n128<128, 0><<<b64(N_pc), 256, 0, stream>>>(x_pc, Wv_pp, bv_pp, v_pp, N_pc);
    gemm_n128<64, 0><<<b64(E_pp), 256, 0, stream>>>(ea_pp, We_pp, be_pp, e_pp, E_pp);
    gemm_n128<128, 1><<<b64(N_pc), 256, 0, stream>>>(x_pc, Wnp_pc, bnp_pc, out_pc, N_pc);
    edge_attn<<<(E_pp * NH + 255) / 256, 256, 0, stream>>>(q_pp, k_pp, v_pp, e_pp, ei_pp,
                                                           den_pp, agg_pp, E_pp);
    norm_agg<<<(N_pc * 128 + 255) / 256, 256, 0, stream>>>(agg_pp, den_pp, N_pc);
    gemm_n128<128, 2><<<b64(N_pc), 256, 0, stream>>>(agg_pp, Wo_pp, bo_pp, out_pc, N_pc);

    // ---- pg (pc -> gr) ----
    gemm_n128<128, 0><<<b64(N_gr), 256, 0, stream>>>(x_gr, Wq_pg, bq_pg, q_pg, N_gr);
    gemm_n128<128, 0><<<b64(N_pc), 256, 0, stream>>>(x_pc, Wk_pg, bk_pg, k_pg, N_pc);
    gemm_n128<128, 0><<<b64(N_pc), 256, 0, stream>>>(x_pc, Wv_pg, bv_pg, v_pg, N_pc);
    gemm_n128<64, 0><<<b64(E_pg), 256, 0, stream>>>(ea_pg, We_pg, be_pg, e_pg, E_pg);
    gemm_n128<128, 1><<<b64(N_gr), 256, 0, stream>>>(x_gr, Wnp_gr, bnp_gr, out_gr, N_gr);
    edge_attn<<<(E_pg * NH + 255) / 256, 256, 0, stream>>>(q_pg, k_pg, v_pg, e_pg, ei_pg,
                                                           den_pg, agg_pg, E_pg);
    norm_agg<<<(N_gr * 128 + 255) / 256, 256, 0, stream>>>(agg_pg, den_pg, N_gr);
    gemm_n128<128, 2><<<b64(N_gr), 256, 0, stream>>>(agg_pg, Wo_pg, bo_pg, out_gr, N_gr);

    // ---- layernorm ----
    layernorm128<<<(N_pc + 3) / 4, 256, 0, stream>>>(out_pc, g_pc, bln_pc, N_pc);
    layernorm128<<<(N_gr + 3) / 4, 256, 0, stream>>>(out_gr, g_gr, bln_gr, N_gr);
}

// Round 2
// 958.356 us; speedup vs baseline: 4.5236x; 4.5236x over previous
//
#include <hip/hip_runtime.h>
#include <hip/hip_bf16.h>
#include <stdint.h>

#define NH 8
#define DH 16

// ---------- helpers ----------
__device__ __forceinline__ unsigned short f2bf(float x) {
    unsigned u = __float_as_uint(x);
    u += 0x7fffu + ((u >> 16) & 1u);   // round-to-nearest-even
    return (unsigned short)(u >> 16);
}
__device__ __forceinline__ float bf2f(unsigned short u) {
    return __uint_as_float(((unsigned)u) << 16);
}

// ---------- GEMM: C[M,128] = A[M,K] @ W[K,128] + bias ----------
// MODE 0: store bf16 ; MODE 1: store f32 ; MODE 2: accumulate into f32
template <int K, int MODE>
__global__ __launch_bounds__(256) void gemm_n128(const float* __restrict__ A,
                                                 const float* __restrict__ W,
                                                 const float* __restrict__ bias,
                                                 void* __restrict__ Cv, int M) {
    __shared__ __align__(16) float As[16 * 68];   // [kk][row], padded stride 68
    __shared__ __align__(16) float Ws[16 * 128];  // [kk][col]

    const int tid = threadIdx.x;
    const int tx = tid & 31;        // col group: cols tx*4 .. tx*4+3
    const int ty = tid >> 5;        // row group: rows ty*8 .. ty*8+7
    const int rowBase = blockIdx.x * 64;

    float acc[8][4];
#pragma unroll
    for (int j = 0; j < 8; ++j)
#pragma unroll
        for (int c = 0; c < 4; ++c) acc[j][c] = 0.f;

    const int arow = tid >> 2, aj = tid & 3;

    for (int kb = 0; kb < K; kb += 16) {
        float4 a4 = make_float4(0.f, 0.f, 0.f, 0.f);
        int gr = rowBase + arow;
        if (gr < M)
            a4 = *reinterpret_cast<const float4*>(&A[(size_t)gr * K + kb + aj * 4]);
        As[(aj * 4 + 0) * 68 + arow] = a4.x;
        As[(aj * 4 + 1) * 68 + arow] = a4.y;
        As[(aj * 4 + 2) * 68 + arow] = a4.z;
        As[(aj * 4 + 3) * 68 + arow] = a4.w;
#pragma unroll
        for (int f = tid; f < 512; f += 256) {
            int kk = f >> 5, c4 = f & 31;
            *reinterpret_cast<float4*>(&Ws[kk * 128 + c4 * 4]) =
                *reinterpret_cast<const float4*>(&W[(size_t)(kb + kk) * 128 + c4 * 4]);
        }
        __syncthreads();
#pragma unroll
        for (int kk = 0; kk < 16; ++kk) {
            float4 wv = *reinterpret_cast<const float4*>(&Ws[kk * 128 + tx * 4]);
            float4 a0 = *reinterpret_cast<const float4*>(&As[kk * 68 + ty * 8]);
            float4 a1 = *reinterpret_cast<const float4*>(&As[kk * 68 + ty * 8 + 4]);
            float av[8] = {a0.x, a0.y, a0.z, a0.w, a1.x, a1.y, a1.z, a1.w};
#pragma unroll
            for (int j = 0; j < 8; ++j) {
                acc[j][0] += av[j] * wv.x;
                acc[j][1] += av[j] * wv.y;
                acc[j][2] += av[j] * wv.z;
                acc[j][3] += av[j] * wv.w;
            }
        }
        __syncthreads();
    }

    float4 bv = *reinterpret_cast<const float4*>(&bias[tx * 4]);
#pragma unroll
    for (int j = 0; j < 8; ++j) {
        int r = rowBase + ty * 8 + j;
        if (r >= M) continue;
        float o0 = acc[j][0] + bv.x, o1 = acc[j][1] + bv.y;
        float o2 = acc[j][2] + bv.z, o3 = acc[j][3] + bv.w;
        if (MODE == 0) {
            unsigned short* C = (unsigned short*)Cv;
            uint2 pk;
            pk.x = (unsigned)f2bf(o0) | ((unsigned)f2bf(o1) << 16);
            pk.y = (unsigned)f2bf(o2) | ((unsigned)f2bf(o3) << 16);
            *reinterpret_cast<uint2*>(&C[(size_t)r * 128 + tx * 4]) = pk;
        } else if (MODE == 1) {
            float* C = (float*)Cv;
            *reinterpret_cast<float4*>(&C[(size_t)r * 128 + tx * 4]) =
                make_float4(o0, o1, o2, o3);
        } else {
            float* C = (float*)Cv;
            float4 pr = *reinterpret_cast<float4*>(&C[(size_t)r * 128 + tx * 4]);
            *reinterpret_cast<float4*>(&C[(size_t)r * 128 + tx * 4]) =
                make_float4(pr.x + o0, pr.y + o1, pr.z + o2, pr.w + o3);
        }
    }
}

// ---------- CSR build ----------
__global__ __launch_bounds__(256) void count_dst(const int* __restrict__ dst,
                                                 int* __restrict__ counts, int E) {
    int t = blockIdx.x * 256 + threadIdx.x;
    if (t < E) atomicAdd(&counts[dst[t]], 1);
}

// single-block exclusive scan: counts[N] -> row_ptr[N+1], cursor[N]
__global__ __launch_bounds__(1024) void scan_rowptr(const int* __restrict__ counts,
                                                    int* __restrict__ row_ptr,
                                                    int* __restrict__ cursor, int N) {
    __shared__ int wsum[16];
    __shared__ int carry_s;
    const int tid = threadIdx.x, lane = tid & 63, w = tid >> 6;
    if (tid == 0) carry_s = 0;
    __syncthreads();
    for (int base = 0; base < N; base += 1024) {
        int i = base + tid;
        int v = (i < N) ? counts[i] : 0;
        int s = v;  // inclusive scan within wave
#pragma unroll
        for (int off = 1; off < 64; off <<= 1) {
            int t = __shfl_up(s, off, 64);
            if (lane >= off) s += t;
        }
        if (lane == 63) wsum[w] = s;
        int carry = carry_s;
        __syncthreads();
        if (w == 0 && lane < 16) {
            int ws = wsum[lane];
#pragma unroll
            for (int off = 1; off < 16; off <<= 1) {
                int t = __shfl_up(ws, off, 64);
                if (lane >= off) ws += t;
            }
            wsum[lane] = ws;  // inclusive over wave sums
        }
        __syncthreads();
        int wexcl = (w == 0) ? 0 : wsum[w - 1];
        int excl = carry + wexcl + (s - v);
        if (i < N) { row_ptr[i] = excl; cursor[i] = excl; }
        __syncthreads();
        if (tid == 0) carry_s = carry + wsum[15];
        __syncthreads();
    }
    if (tid == 0) row_ptr[N] = carry_s;
}

__global__ __launch_bounds__(256) void scatter_edges(const int* __restrict__ dst,
                                                     int* __restrict__ cursor,
                                                     int* __restrict__ eids, int E) {
    int t = blockIdx.x * 256 + threadIdx.x;
    if (t < E) {
        int p = atomicAdd(&cursor[dst[t]], 1);
        eids[p] = t;
    }
}

// ---------- CSR gather attention ----------
// one wave per (dst, 4 heads): lanes split into 4 groups of 16 (head x d)
// two waves (wave parity) cover the 8 heads of one dst.
__global__ __launch_bounds__(256) void attn_gather(const unsigned short* __restrict__ q,
                                                   const unsigned short* __restrict__ k,
                                                   const unsigned short* __restrict__ v,
                                                   const unsigned short* __restrict__ e,
                                                   const int* __restrict__ ei_src,
                                                   const int* __restrict__ row_ptr,
                                                   const int* __restrict__ eids,
                                                   float* __restrict__ agg, int N) {
    int wave = (blockIdx.x * 256 + threadIdx.x) >> 6;
    int dst = wave >> 1;
    if (dst >= N) return;
    int lane = threadIdx.x & 63;
    int col = ((wave & 1) << 6) + lane;  // h*16+d, h = col>>4, d = col&15

    float qf = bf2f(q[(size_t)dst * 128 + col]);
    int beg = row_ptr[dst], end = row_ptr[dst + 1];
    float den = 0.f, acc = 0.f;

    // software-pipeline the index chain
    int eid = 0, src = 0;
    if (beg < end) { eid = eids[beg]; src = ei_src[eid]; }
    for (int i = beg; i < end; ++i) {
        int ce = eid, cs = src;
        if (i + 1 < end) { eid = eids[i + 1]; src = ei_src[eid]; }
        float kf = bf2f(k[(size_t)cs * 128 + col]);
        float vf = bf2f(v[(size_t)cs * 128 + col]);
        float ef = bf2f(e[(size_t)ce * 128 + col]);
        float p = qf * (kf + ef);
        p += __shfl_xor(p, 1, 64);
        p += __shfl_xor(p, 2, 64);
        p += __shfl_xor(p, 4, 64);
        p += __shfl_xor(p, 8, 64);
        float ex = __expf(p * 0.25f);  // scale = 16^-0.5
        den += ex;
        acc += ex * (vf + ef);
    }
    agg[(size_t)dst * 128 + col] = den > 0.f ? acc / den : 0.f;
}

// ---------- layernorm over 128 cols, one wave per row ----------
__global__ __launch_bounds__(256) void layernorm128(float* __restrict__ out,
                                                    const float* __restrict__ g,
                                                    const float* __restrict__ b, int N) {
    int row = blockIdx.x * 4 + (threadIdx.x >> 6);
    int lane = threadIdx.x & 63;
    if (row >= N) return;
    float* p = out + (size_t)row * 128;
    float x0 = p[lane], x1 = p[lane + 64];
    float sum = x0 + x1;
#pragma unroll
    for (int off = 1; off < 64; off <<= 1) sum += __shfl_xor(sum, off, 64);
    float mu = sum * (1.f / 128.f);
    float d0 = x0 - mu, d1 = x1 - mu;
    float vs = d0 * d0 + d1 * d1;
#pragma unroll
    for (int off = 1; off < 64; off <<= 1) vs += __shfl_xor(vs, off, 64);
    float r = rsqrtf(vs * (1.f / 128.f) + 1e-5f);
    p[lane]      = d0 * r * g[lane] + b[lane];
    p[lane + 64] = d1 * r * g[lane + 64] + b[lane + 64];
}

extern "C" void kernel_launch(void* const* d_in, const int* in_sizes, int n_in,
                              void* d_out, int out_size, void* d_ws, size_t ws_size,
                              hipStream_t stream) {
    const float* x_pc  = (const float*)d_in[0];
    const float* x_gr  = (const float*)d_in[1];
    const float* ea_pp = (const float*)d_in[2];
    const float* ea_pg = (const float*)d_in[3];
    const int* ei_pp   = (const int*)d_in[4];
    const int* ei_pg   = (const int*)d_in[5];
    const float *Wq_pp = (const float*)d_in[6],  *bq_pp = (const float*)d_in[7];
    const float *Wk_pp = (const float*)d_in[8],  *bk_pp = (const float*)d_in[9];
    const float *Wv_pp = (const float*)d_in[10], *bv_pp = (const float*)d_in[11];
    const float *We_pp = (const float*)d_in[12], *be_pp = (const float*)d_in[13];
    const float *Wo_pp = (const float*)d_in[14], *bo_pp = (const float*)d_in[15];
    const float *Wq_pg = (const float*)d_in[16], *bq_pg = (const float*)d_in[17];
    const float *Wk_pg = (const float*)d_in[18], *bk_pg = (const float*)d_in[19];
    const float *Wv_pg = (const float*)d_in[20], *bv_pg = (const float*)d_in[21];
    const float *We_pg = (const float*)d_in[22], *be_pg = (const float*)d_in[23];
    const float *Wo_pg = (const float*)d_in[24], *bo_pg = (const float*)d_in[25];
    const float *Wnp_pc = (const float*)d_in[26], *bnp_pc = (const float*)d_in[27];
    const float *g_pc   = (const float*)d_in[28], *bln_pc = (const float*)d_in[29];
    const float *Wnp_gr = (const float*)d_in[30], *bnp_gr = (const float*)d_in[31];
    const float *g_gr   = (const float*)d_in[32], *bln_gr = (const float*)d_in[33];

    const int N_pc = in_sizes[0] / 128;
    const int N_gr = in_sizes[1] / 128;
    const int E_pp = in_sizes[4] / 2;
    const int E_pg = in_sizes[5] / 2;

    char* ws = (char*)d_ws;
    size_t off = 0;
    auto alloc = [&](size_t bytes) -> char* {
        char* p = ws + off;
        off += (bytes + 255) & ~(size_t)255;
        return p;
    };
    unsigned short* q_pp = (unsigned short*)alloc((size_t)N_pc * 128 * 2);
    unsigned short* k_pp = (unsigned short*)alloc((size_t)N_pc * 128 * 2);
    unsigned short* v_pp = (unsigned short*)alloc((size_t)N_pc * 128 * 2);
    unsigned short* e_pp = (unsigned short*)alloc((size_t)E_pp * 128 * 2);
    unsigned short* q_pg = (unsigned short*)alloc((size_t)N_gr * 128 * 2);
    unsigned short* k_pg = (unsigned short*)alloc((size_t)N_pc * 128 * 2);
    unsigned short* v_pg = (unsigned short*)alloc((size_t)N_pc * 128 * 2);
    unsigned short* e_pg = (unsigned short*)alloc((size_t)E_pg * 128 * 2);
    float* agg_pp = (float*)alloc((size_t)N_pc * 128 * 4);
    float* agg_pg = (float*)alloc((size_t)N_gr * 128 * 4);
    int* row_ptr_pp = (int*)alloc((size_t)(N_pc + 1) * 4);
    int* cursor_pp  = (int*)alloc((size_t)N_pc * 4);
    int* eids_pp    = (int*)alloc((size_t)E_pp * 4);
    int* row_ptr_pg = (int*)alloc((size_t)(N_gr + 1) * 4);
    int* cursor_pg  = (int*)alloc((size_t)N_gr * 4);
    int* eids_pg    = (int*)alloc((size_t)E_pg * 4);
    char* zbase = ws + off;  // counts need zeroing each call
    int* counts_pp = (int*)alloc((size_t)N_pc * 4);
    int* counts_pg = (int*)alloc((size_t)N_gr * 4);
    size_t zbytes = (size_t)((ws + off) - zbase);
    hipMemsetAsync(zbase, 0, zbytes, stream);

    float* out_pc = (float*)d_out;
    float* out_gr = out_pc + (size_t)N_pc * 128;

    auto b64 = [](int M) { return (M + 63) / 64; };
    auto bE  = [](int n) { return (n + 255) / 256; };

    const int* dst_pp = ei_pp + E_pp;
    const int* dst_pg = ei_pg + E_pg;

    // ---- CSR build (overlaps nothing, but cheap) ----
    count_dst<<<bE(E_pp), 256, 0, stream>>>(dst_pp, counts_pp, E_pp);
    count_dst<<<bE(E_pg), 256, 0, stream>>>(dst_pg, counts_pg, E_pg);
    scan_rowptr<<<1, 1024, 0, stream>>>(counts_pp, row_ptr_pp, cursor_pp, N_pc);
    scan_rowptr<<<1, 1024, 0, stream>>>(counts_pg, row_ptr_pg, cursor_pg, N_gr);
    scatter_edges<<<bE(E_pp), 256, 0, stream>>>(dst_pp, cursor_pp, eids_pp, E_pp);
    scatter_edges<<<bE(E_pg), 256, 0, stream>>>(dst_pg, cursor_pg, eids_pg, E_pg);

    // ---- projections ----
    gemm_n128<128, 0><<<b64(N_pc), 256, 0, stream>>>(x_pc, Wq_pp, bq_pp, q_pp, N_pc);
    gemm_n128<128, 0><<<b64(N_pc), 256, 0, stream>>>(x_pc, Wk_pp, bk_pp, k_pp, N_pc);
    gemm_n128<128, 0><<<b64(N_pc), 256, 0, stream>>>(x_pc, Wv_pp, bv_pp, v_pp, N_pc);
    gemm_n128<64, 0><<<b64(E_pp), 256, 0, stream>>>(ea_pp, We_pp, be_pp, e_pp, E_pp);
    gemm_n128<128, 1><<<b64(N_pc), 256, 0, stream>>>(x_pc, Wnp_pc, bnp_pc, out_pc, N_pc);
    gemm_n128<128, 0><<<b64(N_gr), 256, 0, stream>>>(x_gr, Wq_pg, bq_pg, q_pg, N_gr);
    gemm_n128<128, 0><<<b64(N_pc), 256, 0, stream>>>(x_pc, Wk_pg, bk_pg, k_pg, N_pc);
    gemm_n128<128, 0><<<b64(N_pc), 256, 0, stream>>>(x_pc, Wv_pg, bv_pg, v_pg, N_pc);
    gemm_n128<64, 0><<<b64(E_pg), 256, 0, stream>>>(ea_pg, We_pg, be_pg, e_pg, E_pg);
    gemm_n128<128, 1><<<b64(N_gr), 256, 0, stream>>>(x_gr, Wnp_gr, bnp_gr, out_gr, N_gr);

    // ---- gather attention (fuses softmax-normalize) ----
    attn_gather<<<(N_pc + 1) / 2, 256, 0, stream>>>(q_pp, k_pp, v_pp, e_pp, ei_pp,
                                                    row_ptr_pp, eids_pp, agg_pp, N_pc);
    attn_gather<<<(N_gr + 1) / 2, 256, 0, stream>>>(q_pg, k_pg, v_pg, e_pg, ei_pg,
                                                    row_ptr_pg, eids_pg, agg_pg, N_gr);

    // ---- output projections (accumulate into node-proj base) ----
    gemm_n128<128, 2><<<b64(N_pc), 256, 0, stream>>>(agg_pp, Wo_pp, bo_pp, out_pc, N_pc);
    gemm_n128<128, 2><<<b64(N_gr), 256, 0, stream>>>(agg_pg, Wo_pg, bo_pg, out_gr, N_gr);

    // ---- layernorm ----
    layernorm128<<<(N_pc + 3) / 4, 256, 0, stream>>>(out_pc, g_pc, bln_pc, N_pc);
    layernorm128<<<(N_gr + 3) / 4, 256, 0, stream>>>(out_gr, g_gr, bln_gr, N_gr);
}

// Round 3
// 743.144 us; speedup vs baseline: 5.8336x; 1.2896x over previous
//
#include <hip/hip_runtime.h>
#include <hip/hip_bf16.h>
#include <stdint.h>

#define NH 8

typedef short short8 __attribute__((ext_vector_type(8)));
typedef float f32x4 __attribute__((ext_vector_type(4)));

// ---------- helpers ----------
__device__ __forceinline__ unsigned short f2bf(float x) {
    unsigned u = __float_as_uint(x);
    u += 0x7fffu + ((u >> 16) & 1u);   // round-to-nearest-even
    return (unsigned short)(u >> 16);
}
__device__ __forceinline__ float bf2f(unsigned short u) {
    return __uint_as_float(((unsigned)u) << 16);
}

// ---------- weight prep: W [K][128] f32 -> Wt [128][K] bf16 ----------
struct WDesc { const float* src; unsigned short* dst; int K; };
struct WPack { WDesc w[12]; };

__global__ __launch_bounds__(256) void prep_weights(WPack p) {
    WDesc d = p.w[blockIdx.x];
    int total = d.K * 128;
    for (int i = threadIdx.x; i < total; i += 256) {
        int n = i / d.K, k = i - n * d.K;            // dst-ordered (coalesced writes)
        d.dst[i] = f2bf(d.src[(size_t)k * 128 + n]);
    }
}

// ---------- MFMA GEMM ----------
// C[M,128] = A[M,K] @ W[K,128] + bias, for NOUT weight matrices sharing A.
// A staged in LDS once (bf16); B staged per-output in 64-k chunks.
// mode 0: store bf16 ; 1: store f32 ; 2: accumulate into f32
struct OutDesc {
    const unsigned short* Wt;  // [128][K] bf16
    const float* bias;         // [128]
    void* out;
    int ldc, coloff, mode;
};
struct DescPack { OutDesc d[6]; };

template <int K, int NOUT, bool GATHER, bool ABF16>
__global__ __launch_bounds__(256) void gemm_mfma(const void* __restrict__ Av,
                                                 const int* __restrict__ idx, int M,
                                                 DescPack dp) {
    constexpr int LDA = K + 8;
    constexpr int LDB = 72;
    __shared__ __align__(16) unsigned short As[64 * LDA];
    __shared__ __align__(16) unsigned short Bs[128 * LDB];

    const int tid = threadIdx.x;
    const int rbase = blockIdx.x * 64;

    // ---- stage A (full K), f32->bf16 or bf16 copy ----
    {
        constexpr int KG = K / 8;
        for (int slot = tid; slot < 64 * KG; slot += 256) {
            int row = slot / KG, kg = slot % KG;
            int gr = rbase + row;
            short8 s8 = {0, 0, 0, 0, 0, 0, 0, 0};
            if (gr < M) {
                int ar = gr;
                if (GATHER) ar = idx[gr];
                if (ABF16) {
                    s8 = *reinterpret_cast<const short8*>(
                        (const unsigned short*)Av + (size_t)ar * K + kg * 8);
                } else {
                    const float* A = (const float*)Av;
                    float4 f0 = *reinterpret_cast<const float4*>(A + (size_t)ar * K + kg * 8);
                    float4 f1 = *reinterpret_cast<const float4*>(A + (size_t)ar * K + kg * 8 + 4);
                    s8[0] = (short)f2bf(f0.x); s8[1] = (short)f2bf(f0.y);
                    s8[2] = (short)f2bf(f0.z); s8[3] = (short)f2bf(f0.w);
                    s8[4] = (short)f2bf(f1.x); s8[5] = (short)f2bf(f1.y);
                    s8[6] = (short)f2bf(f1.z); s8[7] = (short)f2bf(f1.w);
                }
            }
            *reinterpret_cast<short8*>(&As[row * LDA + kg * 8]) = s8;
        }
    }

    const int lane = tid & 63, w = tid >> 6;
    const int rb = (w >> 1) * 32, cb = (w & 1) * 64;  // wave's 32x64 sub-tile
    const int qd = lane >> 4, l16 = lane & 15;

    for (int o = 0; o < NOUT; ++o) {
        OutDesc d = dp.d[o];
        f32x4 acc[2][4];
#pragma unroll
        for (int rt = 0; rt < 2; ++rt)
#pragma unroll
            for (int ct = 0; ct < 4; ++ct) {
                f32x4 z = {0.f, 0.f, 0.f, 0.f};
                acc[rt][ct] = z;
            }

        for (int kc = 0; kc < K; kc += 64) {
            __syncthreads();  // protect As (first pass) / Bs (reuse)
            for (int slot = tid; slot < 128 * 8; slot += 256) {
                int n = slot >> 3, kg = slot & 7;
                *reinterpret_cast<short8*>(&Bs[n * LDB + kg * 8]) =
                    *reinterpret_cast<const short8*>(d.Wt + (size_t)n * K + kc + kg * 8);
            }
            __syncthreads();
#pragma unroll
            for (int ks = 0; ks < 64; ks += 32) {
                short8 af[2], bfr[4];
#pragma unroll
                for (int rt = 0; rt < 2; ++rt)
                    af[rt] = *reinterpret_cast<const short8*>(
                        &As[(rb + rt * 16 + l16) * LDA + kc + ks + qd * 8]);
#pragma unroll
                for (int ct = 0; ct < 4; ++ct)
                    bfr[ct] = *reinterpret_cast<const short8*>(
                        &Bs[(cb + ct * 16 + l16) * LDB + ks + qd * 8]);
#pragma unroll
                for (int rt = 0; rt < 2; ++rt)
#pragma unroll
                    for (int ct = 0; ct < 4; ++ct)
                        acc[rt][ct] = __builtin_amdgcn_mfma_f32_16x16x32_bf16(
                            af[rt], bfr[ct], acc[rt][ct], 0, 0, 0);
            }
        }

        // ---- epilogue ----
#pragma unroll
        for (int ct = 0; ct < 4; ++ct) {
            int col = cb + ct * 16 + l16;
            float bv = d.bias[col];
#pragma unroll
            for (int rt = 0; rt < 2; ++rt) {
                int row0 = rbase + rb + rt * 16 + qd * 4;
#pragma unroll
                for (int r = 0; r < 4; ++r) {
                    int row = row0 + r;
                    if (row < M) {
                        float val = acc[rt][ct][r] + bv;
                        size_t pos = (size_t)row * d.ldc + d.coloff + col;
                        if (d.mode == 0)
                            ((unsigned short*)d.out)[pos] = f2bf(val);
                        else if (d.mode == 1)
                            ((float*)d.out)[pos] = val;
                        else
                            ((float*)d.out)[pos] += val;
                    }
                }
            }
        }
    }
}

// ---------- CSR build ----------
__global__ __launch_bounds__(256) void count_dst(const int* __restrict__ dst,
                                                 int* __restrict__ counts, int E) {
    int t = blockIdx.x * 256 + threadIdx.x;
    if (t < E) atomicAdd(&counts[dst[t]], 1);
}

__global__ __launch_bounds__(1024) void scan_rowptr(const int* __restrict__ counts,
                                                    int* __restrict__ row_ptr,
                                                    int* __restrict__ cursor, int N) {
    __shared__ int wsum[16];
    __shared__ int carry_s;
    const int tid = threadIdx.x, lane = tid & 63, w = tid >> 6;
    if (tid == 0) carry_s = 0;
    __syncthreads();
    for (int base = 0; base < N; base += 1024) {
        int i = base + tid;
        int v = (i < N) ? counts[i] : 0;
        int s = v;
#pragma unroll
        for (int off = 1; off < 64; off <<= 1) {
            int t = __shfl_up(s, off, 64);
            if (lane >= off) s += t;
        }
        if (lane == 63) wsum[w] = s;
        int carry = carry_s;
        __syncthreads();
        if (w == 0 && lane < 16) {
            int ws = wsum[lane];
#pragma unroll
            for (int off = 1; off < 16; off <<= 1) {
                int t = __shfl_up(ws, off, 64);
                if (lane >= off) ws += t;
            }
            wsum[lane] = ws;
        }
        __syncthreads();
        int wexcl = (w == 0) ? 0 : wsum[w - 1];
        int excl = carry + wexcl + (s - v);
        if (i < N) { row_ptr[i] = excl; cursor[i] = excl; }
        __syncthreads();
        if (tid == 0) carry_s = carry + wsum[15];
        __syncthreads();
    }
    if (tid == 0) row_ptr[N] = carry_s;
}

__global__ __launch_bounds__(256) void scatter_edges(const int* __restrict__ src,
                                                     const int* __restrict__ dst,
                                                     int* __restrict__ cursor,
                                                     int* __restrict__ eids,
                                                     int* __restrict__ srcs, int E) {
    int t = blockIdx.x * 256 + threadIdx.x;
    if (t < E) {
        int p = atomicAdd(&cursor[dst[t]], 1);
        eids[p] = t;
        srcs[p] = src[t];
    }
}

// ---------- CSR gather attention ----------
// wave covers 4 heads (64 cols); 2 waves per dst. e and srcs are CSR-ordered
// (sequential); only kv rows are random. agg written bf16.
__global__ __launch_bounds__(256) void attn_gather(const unsigned short* __restrict__ q,
                                                   const unsigned short* __restrict__ kv,
                                                   const unsigned short* __restrict__ e,
                                                   const int* __restrict__ srcs,
                                                   const int* __restrict__ row_ptr,
                                                   unsigned short* __restrict__ agg, int N) {
    int wave = (blockIdx.x * 256 + threadIdx.x) >> 6;
    int dst = wave >> 1;
    if (dst >= N) return;
    int lane = threadIdx.x & 63;
    int col = ((wave & 1) << 6) + lane;  // h*16+d

    float qf = bf2f(q[(size_t)dst * 128 + col]);
    int beg = row_ptr[dst], end = row_ptr[dst + 1];
    float den = 0.f, acc = 0.f;

    int s_next = (beg < end) ? srcs[beg] : 0;
    for (int i = beg; i < end; ++i) {
        int cs = s_next;
        if (i + 1 < end) s_next = srcs[i + 1];
        float kf = bf2f(kv[(size_t)cs * 256 + col]);
        float vf = bf2f(kv[(size_t)cs * 256 + 128 + col]);
        float ef = bf2f(e[(size_t)i * 128 + col]);
        float p = qf * (kf + ef);
        p += __shfl_xor(p, 1, 64);
        p += __shfl_xor(p, 2, 64);
        p += __shfl_xor(p, 4, 64);
        p += __shfl_xor(p, 8, 64);
        float ex = __expf(p * 0.25f);  // scale = 16^-0.5
        den += ex;
        acc += ex * (vf + ef);
    }
    agg[(size_t)dst * 128 + col] = f2bf(den > 0.f ? acc / den : 0.f);
}

// ---------- layernorm over 128 cols, one wave per row ----------
__global__ __launch_bounds__(256) void layernorm128(float* __restrict__ out,
                                                    const float* __restrict__ g,
                                                    const float* __restrict__ b, int N) {
    int row = blockIdx.x * 4 + (threadIdx.x >> 6);
    int lane = threadIdx.x & 63;
    if (row >= N) return;
    float* p = out + (size_t)row * 128;
    float x0 = p[lane], x1 = p[lane + 64];
    float sum = x0 + x1;
#pragma unroll
    for (int off = 1; off < 64; off <<= 1) sum += __shfl_xor(sum, off, 64);
    float mu = sum * (1.f / 128.f);
    float d0 = x0 - mu, d1 = x1 - mu;
    float vs = d0 * d0 + d1 * d1;
#pragma unroll
    for (int off = 1; off < 64; off <<= 1) vs += __shfl_xor(vs, off, 64);
    float r = rsqrtf(vs * (1.f / 128.f) + 1e-5f);
    p[lane]      = d0 * r * g[lane] + b[lane];
    p[lane + 64] = d1 * r * g[lane + 64] + b[lane + 64];
}

extern "C" void kernel_launch(void* const* d_in, const int* in_sizes, int n_in,
                              void* d_out, int out_size, void* d_ws, size_t ws_size,
                              hipStream_t stream) {
    const float* x_pc  = (const float*)d_in[0];
    const float* x_gr  = (const float*)d_in[1];
    const float* ea_pp = (const float*)d_in[2];
    const float* ea_pg = (const float*)d_in[3];
    const int* ei_pp   = (const int*)d_in[4];
    const int* ei_pg   = (const int*)d_in[5];
    const float *Wq_pp = (const float*)d_in[6],  *bq_pp = (const float*)d_in[7];
    const float *Wk_pp = (const float*)d_in[8],  *bk_pp = (const float*)d_in[9];
    const float *Wv_pp = (const float*)d_in[10], *bv_pp = (const float*)d_in[11];
    const float *We_pp = (const float*)d_in[12], *be_pp = (const float*)d_in[13];
    const float *Wo_pp = (const float*)d_in[14], *bo_pp = (const float*)d_in[15];
    const float *Wq_pg = (const float*)d_in[16], *bq_pg = (const float*)d_in[17];
    const float *Wk_pg = (const float*)d_in[18], *bk_pg = (const float*)d_in[19];
    const float *Wv_pg = (const float*)d_in[20], *bv_pg = (const float*)d_in[21];
    const float *We_pg = (const float*)d_in[22], *be_pg = (const float*)d_in[23];
    const float *Wo_pg = (const float*)d_in[24], *bo_pg = (const float*)d_in[25];
    const float *Wnp_pc = (const float*)d_in[26], *bnp_pc = (const float*)d_in[27];
    const float *g_pc   = (const float*)d_in[28], *bln_pc = (const float*)d_in[29];
    const float *Wnp_gr = (const float*)d_in[30], *bnp_gr = (const float*)d_in[31];
    const float *g_gr   = (const float*)d_in[32], *bln_gr = (const float*)d_in[33];

    const int N_pc = in_sizes[0] / 128;
    const int N_gr = in_sizes[1] / 128;
    const int E_pp = in_sizes[4] / 2;
    const int E_pg = in_sizes[5] / 2;

    char* ws = (char*)d_ws;
    size_t off = 0;
    auto alloc = [&](size_t bytes) -> char* {
        char* p = ws + off;
        off += (bytes + 255) & ~(size_t)255;
        return p;
    };
    // transposed bf16 weights
    unsigned short* Wt[12];
    const float* Wsrc[12] = {Wq_pp, Wk_pp, Wv_pp, Wk_pg, Wv_pg, Wnp_pc,
                             Wq_pg, Wnp_gr, We_pp, We_pg, Wo_pp, Wo_pg};
    int Wk[12] = {128, 128, 128, 128, 128, 128, 128, 128, 64, 64, 128, 128};
    for (int i = 0; i < 12; ++i) Wt[i] = (unsigned short*)alloc((size_t)Wk[i] * 128 * 2);

    unsigned short* q_pp  = (unsigned short*)alloc((size_t)N_pc * 128 * 2);
    unsigned short* kv_pp = (unsigned short*)alloc((size_t)N_pc * 256 * 2);
    unsigned short* q_pg  = (unsigned short*)alloc((size_t)N_gr * 128 * 2);
    unsigned short* kv_pg = (unsigned short*)alloc((size_t)N_pc * 256 * 2);
    unsigned short* e_pp  = (unsigned short*)alloc((size_t)E_pp * 128 * 2);
    unsigned short* e_pg  = (unsigned short*)alloc((size_t)E_pg * 128 * 2);
    unsigned short* agg_pp = (unsigned short*)alloc((size_t)N_pc * 128 * 2);
    unsigned short* agg_pg = (unsigned short*)alloc((size_t)N_gr * 128 * 2);
    int* row_ptr_pp = (int*)alloc((size_t)(N_pc + 1) * 4);
    int* cursor_pp  = (int*)alloc((size_t)N_pc * 4);
    int* eids_pp    = (int*)alloc((size_t)E_pp * 4);
    int* srcs_pp    = (int*)alloc((size_t)E_pp * 4);
    int* row_ptr_pg = (int*)alloc((size_t)(N_gr + 1) * 4);
    int* cursor_pg  = (int*)alloc((size_t)N_gr * 4);
    int* eids_pg    = (int*)alloc((size_t)E_pg * 4);
    int* srcs_pg    = (int*)alloc((size_t)E_pg * 4);
    char* zbase = ws + off;
    int* counts_pp = (int*)alloc((size_t)N_pc * 4);
    int* counts_pg = (int*)alloc((size_t)N_gr * 4);
    size_t zbytes = (size_t)((ws + off) - zbase);
    hipMemsetAsync(zbase, 0, zbytes, stream);

    float* out_pc = (float*)d_out;
    float* out_gr = out_pc + (size_t)N_pc * 128;

    auto b64 = [](int M) { return (M + 63) / 64; };
    auto bE  = [](int n) { return (n + 255) / 256; };

    const int* src_pp = ei_pp;
    const int* dst_pp = ei_pp + E_pp;
    const int* src_pg = ei_pg;
    const int* dst_pg = ei_pg + E_pg;

    // ---- weight prep ----
    WPack wp;
    for (int i = 0; i < 12; ++i) wp.w[i] = {Wsrc[i], Wt[i], Wk[i]};
    prep_weights<<<12, 256, 0, stream>>>(wp);

    // ---- CSR build ----
    count_dst<<<bE(E_pp), 256, 0, stream>>>(dst_pp, counts_pp, E_pp);
    count_dst<<<bE(E_pg), 256, 0, stream>>>(dst_pg, counts_pg, E_pg);
    scan_rowptr<<<1, 1024, 0, stream>>>(counts_pp, row_ptr_pp, cursor_pp, N_pc);
    scan_rowptr<<<1, 1024, 0, stream>>>(counts_pg, row_ptr_pg, cursor_pg, N_gr);
    scatter_edges<<<bE(E_pp), 256, 0, stream>>>(src_pp, dst_pp, cursor_pp, eids_pp, srcs_pp, E_pp);
    scatter_edges<<<bE(E_pg), 256, 0, stream>>>(src_pg, dst_pg, cursor_pg, eids_pg, srcs_pg, E_pg);

    // ---- fused projections from x_pc (6 outputs) ----
    DescPack dx;
    dx.d[0] = {Wt[0], bq_pp, q_pp, 128, 0, 0};
    dx.d[1] = {Wt[1], bk_pp, kv_pp, 256, 0, 0};
    dx.d[2] = {Wt[2], bv_pp, kv_pp, 256, 128, 0};
    dx.d[3] = {Wt[3], bk_pg, kv_pg, 256, 0, 0};
    dx.d[4] = {Wt[4], bv_pg, kv_pg, 256, 128, 0};
    dx.d[5] = {Wt[5], bnp_pc, out_pc, 128, 0, 1};
    gemm_mfma<128, 6, false, false><<<b64(N_pc), 256, 0, stream>>>(x_pc, nullptr, N_pc, dx);

    // ---- fused projections from x_gr (2 outputs) ----
    DescPack dg{};
    dg.d[0] = {Wt[6], bq_pg, q_pg, 128, 0, 0};
    dg.d[1] = {Wt[7], bnp_gr, out_gr, 128, 0, 1};
    gemm_mfma<128, 2, false, false><<<b64(N_gr), 256, 0, stream>>>(x_gr, nullptr, N_gr, dg);

    // ---- edge projections, written in CSR order ----
    DescPack de{};
    de.d[0] = {Wt[8], be_pp, e_pp, 128, 0, 0};
    gemm_mfma<64, 1, true, false><<<b64(E_pp), 256, 0, stream>>>(ea_pp, eids_pp, E_pp, de);
    DescPack de2{};
    de2.d[0] = {Wt[9], be_pg, e_pg, 128, 0, 0};
    gemm_mfma<64, 1, true, false><<<b64(E_pg), 256, 0, stream>>>(ea_pg, eids_pg, E_pg, de2);

    // ---- gather attention ----
    attn_gather<<<(N_pc + 1) / 2, 256, 0, stream>>>(q_pp, kv_pp, e_pp, srcs_pp,
                                                    row_ptr_pp, agg_pp, N_pc);
    attn_gather<<<(N_gr + 1) / 2, 256, 0, stream>>>(q_pg, kv_pg, e_pg, srcs_pg,
                                                    row_ptr_pg, agg_pg, N_gr);

    // ---- output projections (accumulate into node-proj base) ----
    DescPack dwo{};
    dwo.d[0] = {Wt[10], bo_pp, out_pc, 128, 0, 2};
    gemm_mfma<128, 1, false, true><<<b64(N_pc), 256, 0, stream>>>(agg_pp, nullptr, N_pc, dwo);
    DescPack dwo2{};
    dwo2.d[0] = {Wt[11], bo_pg, out_gr, 128, 0, 2};
    gemm_mfma<128, 1, false, true><<<b64(N_gr), 256, 0, stream>>>(agg_pg, nullptr, N_gr, dwo2);

    // ---- layernorm ----
    layernorm128<<<(N_pc + 3) / 4, 256, 0, stream>>>(out_pc, g_pc, bln_pc, N_pc);
    layernorm128<<<(N_gr + 3) / 4, 256, 0, stream>>>(out_gr, g_gr, bln_gr, N_gr);
}

// Round 4
// 564.680 us; speedup vs baseline: 7.6773x; 1.3160x over previous
//
#include <hip/hip_runtime.h>
#include <hip/hip_bf16.h>
#include <stdint.h>

typedef short short8 __attribute__((ext_vector_type(8)));
typedef float f32x4 __attribute__((ext_vector_type(4)));

// ---------- helpers ----------
__device__ __forceinline__ unsigned short f2bf(float x) {
    unsigned u = __float_as_uint(x);
    u += 0x7fffu + ((u >> 16) & 1u);   // RNE
    return (unsigned short)(u >> 16);
}
__device__ __forceinline__ float bf2f(unsigned short u) {
    return __uint_as_float(((unsigned)u) << 16);
}

// ---------- weight prep: W [K][128] f32 -> Wt [128][ldd] bf16 (at koff) ----------
struct WDesc { const float* src; unsigned short* dst; int K, ldd, koff; };
struct WPack { WDesc w[12]; };

__global__ __launch_bounds__(256) void prep_weights(WPack p) {
    WDesc d = p.w[blockIdx.x];
    int total = d.K * 128;
    for (int i = threadIdx.x; i < total; i += 256) {
        int n = i / d.K, k = i - n * d.K;
        d.dst[(size_t)n * d.ldd + d.koff + k] = f2bf(d.src[(size_t)k * 128 + n]);
    }
}

// ================= node GEMM: C[M,128] = A[M,128] @ W + bias, NOUT outputs =========
struct NodeOut { const unsigned short* Wt; const float* bias; unsigned short* out; int ldc, coloff; };
struct NodePack { NodeOut d[5]; };

template <int NOUT>
__global__ __launch_bounds__(256) void gemm_node(const float* __restrict__ A, int M, NodePack dp) {
    constexpr int K = 128, LDA = 136, LDB = 72, TLD = 136;
    __shared__ __align__(16) unsigned short As[64 * LDA];
    __shared__ __align__(16) unsigned short Bs[128 * LDB];  // also epilogue tile (TLD)

    const int tid = threadIdx.x;
    const int rbase = blockIdx.x * 64;

    // stage A (f32 -> bf16)
    for (int slot = tid; slot < 64 * 16; slot += 256) {
        int row = slot >> 4, kg = slot & 15;
        int gr = rbase + row;
        short8 s8 = {0, 0, 0, 0, 0, 0, 0, 0};
        if (gr < M) {
            const float* a = A + (size_t)gr * K + kg * 8;
            float4 f0 = *reinterpret_cast<const float4*>(a);
            float4 f1 = *reinterpret_cast<const float4*>(a + 4);
            s8[0] = (short)f2bf(f0.x); s8[1] = (short)f2bf(f0.y);
            s8[2] = (short)f2bf(f0.z); s8[3] = (short)f2bf(f0.w);
            s8[4] = (short)f2bf(f1.x); s8[5] = (short)f2bf(f1.y);
            s8[6] = (short)f2bf(f1.z); s8[7] = (short)f2bf(f1.w);
        }
        *reinterpret_cast<short8*>(&As[row * LDA + kg * 8]) = s8;
    }

    const int lane = tid & 63, w = tid >> 6;
    const int rb = (w >> 1) * 32, cb = (w & 1) * 64;
    const int qd = lane >> 4, l16 = lane & 15;

    for (int o = 0; o < NOUT; ++o) {
        NodeOut d = dp.d[o];
        f32x4 acc[2][4];
#pragma unroll
        for (int rt = 0; rt < 2; ++rt)
#pragma unroll
            for (int ct = 0; ct < 4; ++ct) { f32x4 z = {0.f,0.f,0.f,0.f}; acc[rt][ct] = z; }

        for (int kc = 0; kc < K; kc += 64) {
            __syncthreads();
            for (int slot = tid; slot < 128 * 8; slot += 256) {
                int n = slot >> 3, kg = slot & 7;
                *reinterpret_cast<short8*>(&Bs[n * LDB + kg * 8]) =
                    *reinterpret_cast<const short8*>(d.Wt + (size_t)n * K + kc + kg * 8);
            }
            __syncthreads();
#pragma unroll
            for (int ks = 0; ks < 64; ks += 32) {
                short8 af[2], bfr[4];
#pragma unroll
                for (int rt = 0; rt < 2; ++rt)
                    af[rt] = *reinterpret_cast<const short8*>(
                        &As[(rb + rt * 16 + l16) * LDA + kc + ks + qd * 8]);
#pragma unroll
                for (int ct = 0; ct < 4; ++ct)
                    bfr[ct] = *reinterpret_cast<const short8*>(
                        &Bs[(cb + ct * 16 + l16) * LDB + ks + qd * 8]);
#pragma unroll
                for (int rt = 0; rt < 2; ++rt)
#pragma unroll
                    for (int ct = 0; ct < 4; ++ct)
                        acc[rt][ct] = __builtin_amdgcn_mfma_f32_16x16x32_bf16(
                            af[rt], bfr[ct], acc[rt][ct], 0, 0, 0);
            }
        }

        // epilogue: acc -> LDS tile -> coalesced 16B stores
        __syncthreads();
        unsigned short* tile = Bs;
#pragma unroll
        for (int ct = 0; ct < 4; ++ct) {
            int col = cb + ct * 16 + l16;
            float bv = d.bias[col];
#pragma unroll
            for (int rt = 0; rt < 2; ++rt)
#pragma unroll
                for (int r = 0; r < 4; ++r)
                    tile[(rb + rt * 16 + qd * 4 + r) * TLD + col] = f2bf(acc[rt][ct][r] + bv);
        }
        __syncthreads();
#pragma unroll
        for (int rep = 0; rep < 4; ++rep) {
            int lrow = (tid >> 4) + rep * 16, seg = tid & 15;
            int gr = rbase + lrow;
            if (gr < M)
                *reinterpret_cast<short8*>(&d.out[(size_t)gr * d.ldc + d.coloff + seg * 8]) =
                    *reinterpret_cast<const short8*>(&tile[lrow * TLD + seg * 8]);
        }
    }
}

// ================= edge GEMM: sequential A read, scatter-write rows via pos ========
struct EdgePack {
    const float* A; const unsigned short* Wt; const float* bias;
    const int* pos; unsigned short* out; int M;
};

__global__ __launch_bounds__(256) void gemm_edge(EdgePack p0, EdgePack p1, int B0) {
    constexpr int K = 64, LDA = 72, LDB = 72, TLD = 136;
    __shared__ __align__(16) unsigned short As[64 * LDA];
    __shared__ __align__(16) unsigned short Bs[128 * LDB];

    EdgePack p; int blk;
    if (blockIdx.x < B0) { p = p0; blk = blockIdx.x; } else { p = p1; blk = blockIdx.x - B0; }

    const int tid = threadIdx.x;
    const int rbase = blk * 64;

    for (int slot = tid; slot < 64 * 8; slot += 256) {
        int row = slot >> 3, kg = slot & 7;
        int gr = rbase + row;
        short8 s8 = {0, 0, 0, 0, 0, 0, 0, 0};
        if (gr < p.M) {
            const float* a = p.A + (size_t)gr * K + kg * 8;
            float4 f0 = *reinterpret_cast<const float4*>(a);
            float4 f1 = *reinterpret_cast<const float4*>(a + 4);
            s8[0] = (short)f2bf(f0.x); s8[1] = (short)f2bf(f0.y);
            s8[2] = (short)f2bf(f0.z); s8[3] = (short)f2bf(f0.w);
            s8[4] = (short)f2bf(f1.x); s8[5] = (short)f2bf(f1.y);
            s8[6] = (short)f2bf(f1.z); s8[7] = (short)f2bf(f1.w);
        }
        *reinterpret_cast<short8*>(&As[row * LDA + kg * 8]) = s8;
    }
    for (int slot = tid; slot < 128 * 8; slot += 256) {
        int n = slot >> 3, kg = slot & 7;
        *reinterpret_cast<short8*>(&Bs[n * LDB + kg * 8]) =
            *reinterpret_cast<const short8*>(p.Wt + (size_t)n * K + kg * 8);
    }
    __syncthreads();

    const int lane = tid & 63, w = tid >> 6;
    const int rb = (w >> 1) * 32, cb = (w & 1) * 64;
    const int qd = lane >> 4, l16 = lane & 15;

    f32x4 acc[2][4];
#pragma unroll
    for (int rt = 0; rt < 2; ++rt)
#pragma unroll
        for (int ct = 0; ct < 4; ++ct) { f32x4 z = {0.f,0.f,0.f,0.f}; acc[rt][ct] = z; }

#pragma unroll
    for (int ks = 0; ks < 64; ks += 32) {
        short8 af[2], bfr[4];
#pragma unroll
        for (int rt = 0; rt < 2; ++rt)
            af[rt] = *reinterpret_cast<const short8*>(&As[(rb + rt * 16 + l16) * LDA + ks + qd * 8]);
#pragma unroll
        for (int ct = 0; ct < 4; ++ct)
            bfr[ct] = *reinterpret_cast<const short8*>(&Bs[(cb + ct * 16 + l16) * LDB + ks + qd * 8]);
#pragma unroll
        for (int rt = 0; rt < 2; ++rt)
#pragma unroll
            for (int ct = 0; ct < 4; ++ct)
                acc[rt][ct] = __builtin_amdgcn_mfma_f32_16x16x32_bf16(
                    af[rt], bfr[ct], acc[rt][ct], 0, 0, 0);
    }

    __syncthreads();
    unsigned short* tile = Bs;
#pragma unroll
    for (int ct = 0; ct < 4; ++ct) {
        int col = cb + ct * 16 + l16;
        float bv = p.bias[col];
#pragma unroll
        for (int rt = 0; rt < 2; ++rt)
#pragma unroll
            for (int r = 0; r < 4; ++r)
                tile[(rb + rt * 16 + qd * 4 + r) * TLD + col] = f2bf(acc[rt][ct][r] + bv);
    }
    __syncthreads();
#pragma unroll
    for (int rep = 0; rep < 4; ++rep) {
        int lrow = (tid >> 4) + rep * 16, seg = tid & 15;
        int gr = rbase + lrow;
        if (gr < p.M) {
            int dp = p.pos[gr];
            *reinterpret_cast<short8*>(&p.out[(size_t)dp * 128 + seg * 8]) =
                *reinterpret_cast<const short8*>(&tile[lrow * TLD + seg * 8]);
        }
    }
}

// ===== output GEMM: out = LN( [agg|x] @ [Wo;Wnp] + bo + bnp ) with g,b ===========
struct OutPack {
    const unsigned short* Aagg; const float* Ax;
    const unsigned short* Wt;   // [128][256]
    const float *bo, *bnp, *g, *bln; float* out; int M;
};

__global__ __launch_bounds__(256) void gemm_out_ln(OutPack p0, OutPack p1, int B0) {
    constexpr int K = 256, LDA = 264, LDB = 72, FTLD = 132;
    __shared__ __align__(16) char smemA[64 * LDA * 2];      // As bf16 / f32 LN tile
    __shared__ __align__(16) unsigned short Bs[128 * LDB];
    unsigned short* As = (unsigned short*)smemA;

    OutPack p; int blk;
    if (blockIdx.x < B0) { p = p0; blk = blockIdx.x; } else { p = p1; blk = blockIdx.x - B0; }

    const int tid = threadIdx.x;
    const int rbase = blk * 64;

    // stage A: k<128 from agg (bf16), k>=128 from x (f32)
    for (int slot = tid; slot < 64 * 32; slot += 256) {
        int row = slot >> 5, kg = slot & 31;
        int gr = rbase + row;
        short8 s8 = {0, 0, 0, 0, 0, 0, 0, 0};
        if (gr < p.M) {
            if (kg < 16) {
                s8 = *reinterpret_cast<const short8*>(p.Aagg + (size_t)gr * 128 + kg * 8);
            } else {
                const float* a = p.Ax + (size_t)gr * 128 + (kg - 16) * 8;
                float4 f0 = *reinterpret_cast<const float4*>(a);
                float4 f1 = *reinterpret_cast<const float4*>(a + 4);
                s8[0] = (short)f2bf(f0.x); s8[1] = (short)f2bf(f0.y);
                s8[2] = (short)f2bf(f0.z); s8[3] = (short)f2bf(f0.w);
                s8[4] = (short)f2bf(f1.x); s8[5] = (short)f2bf(f1.y);
                s8[6] = (short)f2bf(f1.z); s8[7] = (short)f2bf(f1.w);
            }
        }
        *reinterpret_cast<short8*>(&As[row * LDA + kg * 8]) = s8;
    }

    const int lane = tid & 63, w = tid >> 6;
    const int rb = (w >> 1) * 32, cb = (w & 1) * 64;
    const int qd = lane >> 4, l16 = lane & 15;

    f32x4 acc[2][4];
#pragma unroll
    for (int rt = 0; rt < 2; ++rt)
#pragma unroll
        for (int ct = 0; ct < 4; ++ct) { f32x4 z = {0.f,0.f,0.f,0.f}; acc[rt][ct] = z; }

    for (int kc = 0; kc < K; kc += 64) {
        __syncthreads();
        for (int slot = tid; slot < 128 * 8; slot += 256) {
            int n = slot >> 3, kg = slot & 7;
            *reinterpret_cast<short8*>(&Bs[n * LDB + kg * 8]) =
                *reinterpret_cast<const short8*>(p.Wt + (size_t)n * K + kc + kg * 8);
        }
        __syncthreads();
#pragma unroll
        for (int ks = 0; ks < 64; ks += 32) {
            short8 af[2], bfr[4];
#pragma unroll
            for (int rt = 0; rt < 2; ++rt)
                af[rt] = *reinterpret_cast<const short8*>(
                    &As[(rb + rt * 16 + l16) * LDA + kc + ks + qd * 8]);
#pragma unroll
            for (int ct = 0; ct < 4; ++ct)
                bfr[ct] = *reinterpret_cast<const short8*>(
                    &Bs[(cb + ct * 16 + l16) * LDB + ks + qd * 8]);
#pragma unroll
            for (int rt = 0; rt < 2; ++rt)
#pragma unroll
                for (int ct = 0; ct < 4; ++ct)
                    acc[rt][ct] = __builtin_amdgcn_mfma_f32_16x16x32_bf16(
                        af[rt], bfr[ct], acc[rt][ct], 0, 0, 0);
        }
    }

    // epilogue: f32 tile (alias As), per-row LayerNorm
    __syncthreads();
    float* ftile = (float*)smemA;
#pragma unroll
    for (int ct = 0; ct < 4; ++ct) {
        int col = cb + ct * 16 + l16;
        float bv = p.bo[col] + p.bnp[col];
#pragma unroll
        for (int rt = 0; rt < 2; ++rt)
#pragma unroll
            for (int r = 0; r < 4; ++r)
                ftile[(rb + rt * 16 + qd * 4 + r) * FTLD + col] = acc[rt][ct][r] + bv;
    }
    __syncthreads();

    int r = tid >> 2, q4 = tid & 3;
    const float* rowp = &ftile[r * FTLD + q4 * 32];
    float s = 0.f, sq = 0.f;
#pragma unroll
    for (int j = 0; j < 8; ++j) {
        float4 v = *reinterpret_cast<const float4*>(rowp + j * 4);
        s += v.x + v.y + v.z + v.w;
        sq += v.x * v.x + v.y * v.y + v.z * v.z + v.w * v.w;
    }
    s += __shfl_xor(s, 1, 64);  s += __shfl_xor(s, 2, 64);
    sq += __shfl_xor(sq, 1, 64); sq += __shfl_xor(sq, 2, 64);
    float mu = s * (1.f / 128.f);
    float var = sq * (1.f / 128.f) - mu * mu;
    float rs = rsqrtf(var + 1e-5f);
    int gr = rbase + r;
    if (gr < p.M) {
#pragma unroll
        for (int j = 0; j < 8; ++j) {
            float4 v = *reinterpret_cast<const float4*>(rowp + j * 4);
            int c = q4 * 32 + j * 4;
            float4 gg = *reinterpret_cast<const float4*>(p.g + c);
            float4 bb = *reinterpret_cast<const float4*>(p.bln + c);
            float4 o;
            o.x = (v.x - mu) * rs * gg.x + bb.x;
            o.y = (v.y - mu) * rs * gg.y + bb.y;
            o.z = (v.z - mu) * rs * gg.z + bb.z;
            o.w = (v.w - mu) * rs * gg.w + bb.w;
            *reinterpret_cast<float4*>(&p.out[(size_t)gr * 128 + c]) = o;
        }
    }
}

// ================= CSR build =================
__global__ __launch_bounds__(256) void count_both(const int* __restrict__ d0, int E0, int* c0,
                                                  const int* __restrict__ d1, int E1, int* c1) {
    int t = blockIdx.x * 256 + threadIdx.x;
    if (t < E0) atomicAdd(&c0[d0[t]], 1);
    else if (t < E0 + E1) atomicAdd(&c1[d1[t - E0]], 1);
}

__global__ __launch_bounds__(1024) void scan_partial(const int* c0, int N0, int* rp0, int* bs0, int B0,
                                                     const int* c1, int N1, int* rp1, int* bs1) {
    __shared__ int wsum[16];
    const int* c; int* rp; int* bs; int N; int blk;
    if ((int)blockIdx.x < B0) { c = c0; rp = rp0; bs = bs0; N = N0; blk = blockIdx.x; }
    else { c = c1; rp = rp1; bs = bs1; N = N1; blk = blockIdx.x - B0; }
    int tid = threadIdx.x, lane = tid & 63, w = tid >> 6;
    int i = blk * 1024 + tid;
    int v = (i < N) ? c[i] : 0;
    int s = v;
#pragma unroll
    for (int off = 1; off < 64; off <<= 1) {
        int t = __shfl_up(s, off, 64);
        if (lane >= off) s += t;
    }
    if (lane == 63) wsum[w] = s;
    __syncthreads();
    if (w == 0 && lane < 16) {
        int ws = wsum[lane];
#pragma unroll
        for (int off = 1; off < 16; off <<= 1) {
            int t = __shfl_up(ws, off, 64);
            if (lane >= off) ws += t;
        }
        wsum[lane] = ws;
    }
    __syncthreads();
    int wexcl = (w == 0) ? 0 : wsum[w - 1];
    if (i < N) rp[i] = wexcl + s - v;
    if (tid == 0) bs[blk] = wsum[15];
}

__global__ __launch_bounds__(128) void scan_mid(const int* bs0, int* off0, int B0, int* rpN0,
                                                const int* bs1, int* off1, int B1, int* rpN1) {
    int w = threadIdx.x >> 6, lane = threadIdx.x & 63;
    const int* bs = w ? bs1 : bs0;
    int* off = w ? off1 : off0;
    int B = w ? B1 : B0;
    int* rpN = w ? rpN1 : rpN0;
    int v = (lane < B) ? bs[lane] : 0;
    int s = v;
#pragma unroll
    for (int o = 1; o < 64; o <<= 1) {
        int t = __shfl_up(s, o, 64);
        if (lane >= o) s += t;
    }
    if (lane < B) off[lane] = s - v;
    int total = __shfl(s, B - 1, 64);
    if (lane == 0) *rpN = total;
}

__global__ __launch_bounds__(1024) void scan_add(int* rp0, int* cur0, const int* off0, int N0, int B0,
                                                 int* rp1, int* cur1, const int* off1, int N1) {
    int* rp; int* cur; const int* off; int N; int blk;
    if ((int)blockIdx.x < B0) { rp = rp0; cur = cur0; off = off0; N = N0; blk = blockIdx.x; }
    else { rp = rp1; cur = cur1; off = off1; N = N1; blk = blockIdx.x - B0; }
    int i = blk * 1024 + threadIdx.x;
    if (i < N) {
        int vv = rp[i] + off[blk];
        rp[i] = vv;
        cur[i] = vv;
    }
}

__global__ __launch_bounds__(256) void scatter_both(
    const int* __restrict__ s0, const int* __restrict__ d0, int E0, int* cur0, int* pos0, int* srcs0,
    const int* __restrict__ s1, const int* __restrict__ d1, int E1, int* cur1, int* pos1, int* srcs1) {
    int t = blockIdx.x * 256 + threadIdx.x;
    if (t < E0) {
        int p = atomicAdd(&cur0[d0[t]], 1);
        pos0[t] = p;
        srcs0[p] = s0[t];
    } else if (t < E0 + E1) {
        int tt = t - E0;
        int p = atomicAdd(&cur1[d1[tt]], 1);
        pos1[tt] = p;
        srcs1[p] = s1[tt];
    }
}

// ================= CSR gather attention (2-deep pipelined) =================
struct AttnPack {
    const unsigned short *q, *kv, *e;
    const int *srcs, *row_ptr;
    unsigned short* agg; int N;
};

__global__ __launch_bounds__(256) void attn_gather(AttnPack a0, AttnPack a1, int B0) {
    AttnPack a; int blk;
    if ((int)blockIdx.x < B0) { a = a0; blk = blockIdx.x; } else { a = a1; blk = blockIdx.x - B0; }
    int wl = (blk * 256 + threadIdx.x) >> 6;
    int dst = wl >> 1;
    if (dst >= a.N) return;
    int lane = threadIdx.x & 63;
    int col = ((wl & 1) << 6) + lane;

    float qf = bf2f(a.q[(size_t)dst * 128 + col]);
    int beg = a.row_ptr[dst], end = a.row_ptr[dst + 1];
    float den = 0.f, acc = 0.f;

    float kfC = 0.f, vfC = 0.f, efC = 0.f;
    int sB = 0;
    if (beg < end) {
        int s0 = a.srcs[beg];
        kfC = bf2f(a.kv[(size_t)s0 * 256 + col]);
        vfC = bf2f(a.kv[(size_t)s0 * 256 + 128 + col]);
        efC = bf2f(a.e[(size_t)beg * 128 + col]);
        if (beg + 1 < end) sB = a.srcs[beg + 1];
    }
    for (int i = beg; i < end; ++i) {
        float kfN = 0.f, vfN = 0.f, efN = 0.f;
        int sC = 0;
        if (i + 1 < end) {
            kfN = bf2f(a.kv[(size_t)sB * 256 + col]);
            vfN = bf2f(a.kv[(size_t)sB * 256 + 128 + col]);
            efN = bf2f(a.e[(size_t)(i + 1) * 128 + col]);
            if (i + 2 < end) sC = a.srcs[i + 2];
        }
        float p = qf * (kfC + efC);
        p += __shfl_xor(p, 1, 64);
        p += __shfl_xor(p, 2, 64);
        p += __shfl_xor(p, 4, 64);
        p += __shfl_xor(p, 8, 64);
        float ex = __expf(p * 0.25f);
        den += ex;
        acc += ex * (vfC + efC);
        kfC = kfN; vfC = vfN; efC = efN; sB = sC;
    }
    a.agg[(size_t)dst * 128 + col] = f2bf(den > 0.f ? acc / den : 0.f);
}

extern "C" void kernel_launch(void* const* d_in, const int* in_sizes, int n_in,
                              void* d_out, int out_size, void* d_ws, size_t ws_size,
                              hipStream_t stream) {
    const float* x_pc  = (const float*)d_in[0];
    const float* x_gr  = (const float*)d_in[1];
    const float* ea_pp = (const float*)d_in[2];
    const float* ea_pg = (const float*)d_in[3];
    const int* ei_pp   = (const int*)d_in[4];
    const int* ei_pg   = (const int*)d_in[5];
    const float *Wq_pp = (const float*)d_in[6],  *bq_pp = (const float*)d_in[7];
    const float *Wk_pp = (const float*)d_in[8],  *bk_pp = (const float*)d_in[9];
    const float *Wv_pp = (const float*)d_in[10], *bv_pp = (const float*)d_in[11];
    const float *We_pp = (const float*)d_in[12], *be_pp = (const float*)d_in[13];
    const float *Wo_pp = (const float*)d_in[14], *bo_pp = (const float*)d_in[15];
    const float *Wq_pg = (const float*)d_in[16], *bq_pg = (const float*)d_in[17];
    const float *Wk_pg = (const float*)d_in[18], *bk_pg = (const float*)d_in[19];
    const float *Wv_pg = (const float*)d_in[20], *bv_pg = (const float*)d_in[21];
    const float *We_pg = (const float*)d_in[22], *be_pg = (const float*)d_in[23];
    const float *Wo_pg = (const float*)d_in[24], *bo_pg = (const float*)d_in[25];
    const float *Wnp_pc = (const float*)d_in[26], *bnp_pc = (const float*)d_in[27];
    const float *g_pc   = (const float*)d_in[28], *bln_pc = (const float*)d_in[29];
    const float *Wnp_gr = (const float*)d_in[30], *bnp_gr = (const float*)d_in[31];
    const float *g_gr   = (const float*)d_in[32], *bln_gr = (const float*)d_in[33];

    const int N_pc = in_sizes[0] / 128;
    const int N_gr = in_sizes[1] / 128;
    const int E_pp = in_sizes[4] / 2;
    const int E_pg = in_sizes[5] / 2;

    char* ws = (char*)d_ws;
    size_t off = 0;
    auto alloc = [&](size_t bytes) -> char* {
        char* p = ws + off;
        off += (bytes + 255) & ~(size_t)255;
        return p;
    };
    // bf16 transposed weights
    unsigned short* Wt_q_pp = (unsigned short*)alloc(128 * 128 * 2);
    unsigned short* Wt_k_pp = (unsigned short*)alloc(128 * 128 * 2);
    unsigned short* Wt_v_pp = (unsigned short*)alloc(128 * 128 * 2);
    unsigned short* Wt_k_pg = (unsigned short*)alloc(128 * 128 * 2);
    unsigned short* Wt_v_pg = (unsigned short*)alloc(128 * 128 * 2);
    unsigned short* Wt_q_pg = (unsigned short*)alloc(128 * 128 * 2);
    unsigned short* Wt_e_pp = (unsigned short*)alloc(64 * 128 * 2);
    unsigned short* Wt_e_pg = (unsigned short*)alloc(64 * 128 * 2);
    unsigned short* Wt_cat_pp = (unsigned short*)alloc(256 * 128 * 2);  // [128][256]
    unsigned short* Wt_cat_gr = (unsigned short*)alloc(256 * 128 * 2);

    unsigned short* q_pp  = (unsigned short*)alloc((size_t)N_pc * 128 * 2);
    unsigned short* kv_pp = (unsigned short*)alloc((size_t)N_pc * 256 * 2);
    unsigned short* q_pg  = (unsigned short*)alloc((size_t)N_gr * 128 * 2);
    unsigned short* kv_pg = (unsigned short*)alloc((size_t)N_pc * 256 * 2);
    unsigned short* e_pp  = (unsigned short*)alloc((size_t)E_pp * 128 * 2);
    unsigned short* e_pg  = (unsigned short*)alloc((size_t)E_pg * 128 * 2);
    unsigned short* agg_pp = (unsigned short*)alloc((size_t)N_pc * 128 * 2);
    unsigned short* agg_pg = (unsigned short*)alloc((size_t)N_gr * 128 * 2);
    int* row_ptr_pp = (int*)alloc((size_t)(N_pc + 1) * 4);
    int* cursor_pp  = (int*)alloc((size_t)N_pc * 4);
    int* pos_pp     = (int*)alloc((size_t)E_pp * 4);
    int* srcs_pp    = (int*)alloc((size_t)E_pp * 4);
    int* row_ptr_pg = (int*)alloc((size_t)(N_gr + 1) * 4);
    int* cursor_pg  = (int*)alloc((size_t)N_gr * 4);
    int* pos_pg     = (int*)alloc((size_t)E_pg * 4);
    int* srcs_pg    = (int*)alloc((size_t)E_pg * 4);
    int* bsum_pp    = (int*)alloc(64 * 4);
    int* boff_pp    = (int*)alloc(64 * 4);
    int* bsum_pg    = (int*)alloc(64 * 4);
    int* boff_pg    = (int*)alloc(64 * 4);
    char* zbase = ws + off;
    int* counts_pp = (int*)alloc((size_t)N_pc * 4);
    int* counts_pg = (int*)alloc((size_t)N_gr * 4);
    size_t zbytes = (size_t)((ws + off) - zbase);
    hipMemsetAsync(zbase, 0, zbytes, stream);

    float* out_pc = (float*)d_out;
    float* out_gr = out_pc + (size_t)N_pc * 128;

    const int* src_pp = ei_pp;
    const int* dst_pp = ei_pp + E_pp;
    const int* src_pg = ei_pg;
    const int* dst_pg = ei_pg + E_pg;

    // ---- weight prep ----
    WPack wp;
    wp.w[0]  = {Wq_pp, Wt_q_pp, 128, 128, 0};
    wp.w[1]  = {Wk_pp, Wt_k_pp, 128, 128, 0};
    wp.w[2]  = {Wv_pp, Wt_v_pp, 128, 128, 0};
    wp.w[3]  = {Wk_pg, Wt_k_pg, 128, 128, 0};
    wp.w[4]  = {Wv_pg, Wt_v_pg, 128, 128, 0};
    wp.w[5]  = {Wq_pg, Wt_q_pg, 128, 128, 0};
    wp.w[6]  = {We_pp, Wt_e_pp, 64, 64, 0};
    wp.w[7]  = {We_pg, Wt_e_pg, 64, 64, 0};
    wp.w[8]  = {Wo_pp, Wt_cat_pp, 128, 256, 0};
    wp.w[9]  = {Wnp_pc, Wt_cat_pp, 128, 256, 128};
    wp.w[10] = {Wo_pg, Wt_cat_gr, 128, 256, 0};
    wp.w[11] = {Wnp_gr, Wt_cat_gr, 128, 256, 128};
    prep_weights<<<12, 256, 0, stream>>>(wp);

    // ---- CSR build ----
    const int Bs_pp = (N_pc + 1023) / 1024, Bs_pg = (N_gr + 1023) / 1024;
    const int gE = (E_pp + E_pg + 255) / 256;
    count_both<<<gE, 256, 0, stream>>>(dst_pp, E_pp, counts_pp, dst_pg, E_pg, counts_pg);
    scan_partial<<<Bs_pp + Bs_pg, 1024, 0, stream>>>(counts_pp, N_pc, row_ptr_pp, bsum_pp, Bs_pp,
                                                     counts_pg, N_gr, row_ptr_pg, bsum_pg);
    scan_mid<<<1, 128, 0, stream>>>(bsum_pp, boff_pp, Bs_pp, &row_ptr_pp[N_pc],
                                    bsum_pg, boff_pg, Bs_pg, &row_ptr_pg[N_gr]);
    scan_add<<<Bs_pp + Bs_pg, 1024, 0, stream>>>(row_ptr_pp, cursor_pp, boff_pp, N_pc, Bs_pp,
                                                 row_ptr_pg, cursor_pg, boff_pg, N_gr);
    scatter_both<<<gE, 256, 0, stream>>>(src_pp, dst_pp, E_pp, cursor_pp, pos_pp, srcs_pp,
                                         src_pg, dst_pg, E_pg, cursor_pg, pos_pg, srcs_pg);

    // ---- node projections ----
    NodePack np;
    np.d[0] = {Wt_q_pp, bq_pp, q_pp, 128, 0};
    np.d[1] = {Wt_k_pp, bk_pp, kv_pp, 256, 0};
    np.d[2] = {Wt_v_pp, bv_pp, kv_pp, 256, 128};
    np.d[3] = {Wt_k_pg, bk_pg, kv_pg, 256, 0};
    np.d[4] = {Wt_v_pg, bv_pg, kv_pg, 256, 128};
    gemm_node<5><<<(N_pc + 63) / 64, 256, 0, stream>>>(x_pc, N_pc, np);
    NodePack ng{};
    ng.d[0] = {Wt_q_pg, bq_pg, q_pg, 128, 0};
    gemm_node<1><<<(N_gr + 63) / 64, 256, 0, stream>>>(x_gr, N_gr, ng);

    // ---- edge projections: sequential read, CSR-scatter write ----
    EdgePack ep0 = {ea_pp, Wt_e_pp, be_pp, pos_pp, e_pp, E_pp};
    EdgePack ep1 = {ea_pg, Wt_e_pg, be_pg, pos_pg, e_pg, E_pg};
    int Be0 = (E_pp + 63) / 64, Be1 = (E_pg + 63) / 64;
    gemm_edge<<<Be0 + Be1, 256, 0, stream>>>(ep0, ep1, Be0);

    // ---- gather attention ----
    AttnPack ap0 = {q_pp, kv_pp, e_pp, srcs_pp, row_ptr_pp, agg_pp, N_pc};
    AttnPack ap1 = {q_pg, kv_pg, e_pg, srcs_pg, row_ptr_pg, agg_pg, N_gr};
    int Ba0 = (N_pc + 1) / 2, Ba1 = (N_gr + 1) / 2;
    attn_gather<<<Ba0 + Ba1, 256, 0, stream>>>(ap0, ap1, Ba0);

    // ---- output GEMM + residual + LayerNorm ----
    OutPack op0 = {agg_pp, x_pc, Wt_cat_pp, bo_pp, bnp_pc, g_pc, bln_pc, out_pc, N_pc};
    OutPack op1 = {agg_pg, x_gr, Wt_cat_gr, bo_pg, bnp_gr, g_gr, bln_gr, out_gr, N_gr};
    int Bo0 = (N_pc + 63) / 64, Bo1 = (N_gr + 63) / 64;
    gemm_out_ln<<<Bo0 + Bo1, 256, 0, stream>>>(op0, op1, Bo0);
}

// Round 5
// 532.779 us; speedup vs baseline: 8.1370x; 1.0599x over previous
//
#include <hip/hip_runtime.h>
#include <hip/hip_bf16.h>
#include <stdint.h>

typedef short short8 __attribute__((ext_vector_type(8)));
typedef float f32x4 __attribute__((ext_vector_type(4)));

// ---------- helpers ----------
__device__ __forceinline__ unsigned short f2bf(float x) {
    unsigned u = __float_as_uint(x);
    u += 0x7fffu + ((u >> 16) & 1u);   // RNE
    return (unsigned short)(u >> 16);
}
__device__ __forceinline__ float bflo(unsigned u) { return __uint_as_float(u << 16); }
__device__ __forceinline__ float bfhi(unsigned u) { return __uint_as_float(u & 0xffff0000u); }

// ---------- weight prep (+ degree count, fused) ----------
// W [K][128] f32 -> Wt [128][ldd] bf16 at koff; perm=1 applies paired-row permutation
struct WDesc { const float* src; unsigned short* dst; int K, ldd, koff, perm; };
struct WPack { WDesc w[12]; };

__global__ __launch_bounds__(256) void prep_and_count(WPack p,
        const int* __restrict__ d0, int E0, int* c0,
        const int* __restrict__ d1, int E1, int* c1, int nPrep) {
    if ((int)blockIdx.x < nPrep) {
        int wi = blockIdx.x >> 2, chunk = blockIdx.x & 3;
        WDesc d = p.w[wi];
        int total = d.K * 128, cs = total >> 2;
        int lo = chunk * cs, hi = lo + cs;
        for (int i = lo + threadIdx.x; i < hi; i += 256) {
            int n = i / d.K, k = i - n * d.K;
            int kk = d.perm ? (2 * (k & 63) + (k >> 6)) : k;
            d.dst[(size_t)n * d.ldd + d.koff + kk] = f2bf(d.src[(size_t)k * 128 + n]);
        }
    } else {
        int t = (blockIdx.x - nPrep) * 256 + threadIdx.x;
        if (t < E0) atomicAdd(&c0[d0[t]], 1);
        else if (t < E0 + E1) atomicAdd(&c1[d1[t - E0]], 1);
    }
}

// ================= node GEMM: paired bf16 outputs, two inputs in one launch =======
struct NodeOut { const unsigned short* Wt; const float* bias; unsigned int* out; int ldc, coloff; };
struct NodePack { NodeOut d[5]; int nout; };

__global__ __launch_bounds__(256) void gemm_node(const float* __restrict__ A0, int M0, NodePack p0,
                                                 int B0,
                                                 const float* __restrict__ A1, int M1, NodePack p1) {
    constexpr int K = 128, LDA = 136, LDB = 72, TLD = 133;
    __shared__ __align__(16) unsigned short As[64 * LDA];
    __shared__ __align__(16) unsigned short Bs[128 * LDB];  // also epilogue tile (TLD)

    const float* A; int M; NodePack dp; int blk;
    if ((int)blockIdx.x < B0) { A = A0; M = M0; dp = p0; blk = blockIdx.x; }
    else { A = A1; M = M1; dp = p1; blk = blockIdx.x - B0; }

    const int tid = threadIdx.x;
    const int rbase = blk * 64;

    for (int slot = tid; slot < 64 * 16; slot += 256) {
        int row = slot >> 4, kg = slot & 15;
        int gr = rbase + row;
        short8 s8 = {0, 0, 0, 0, 0, 0, 0, 0};
        if (gr < M) {
            const float* a = A + (size_t)gr * K + kg * 8;
            float4 f0 = *reinterpret_cast<const float4*>(a);
            float4 f1 = *reinterpret_cast<const float4*>(a + 4);
            s8[0] = (short)f2bf(f0.x); s8[1] = (short)f2bf(f0.y);
            s8[2] = (short)f2bf(f0.z); s8[3] = (short)f2bf(f0.w);
            s8[4] = (short)f2bf(f1.x); s8[5] = (short)f2bf(f1.y);
            s8[6] = (short)f2bf(f1.z); s8[7] = (short)f2bf(f1.w);
        }
        *reinterpret_cast<short8*>(&As[row * LDA + kg * 8]) = s8;
    }

    const int lane = tid & 63, w = tid >> 6;
    const int rb = (w >> 1) * 32, cb = (w & 1) * 64;
    const int qd = lane >> 4, l16 = lane & 15;

    for (int o = 0; o < dp.nout; ++o) {
        NodeOut d = dp.d[o];
        f32x4 acc[2][4];
#pragma unroll
        for (int rt = 0; rt < 2; ++rt)
#pragma unroll
            for (int ct = 0; ct < 4; ++ct) { f32x4 z = {0.f,0.f,0.f,0.f}; acc[rt][ct] = z; }

        for (int kc = 0; kc < K; kc += 64) {
            __syncthreads();
            for (int slot = tid; slot < 128 * 8; slot += 256) {
                int n = slot >> 3, kg = slot & 7;
                *reinterpret_cast<short8*>(&Bs[n * LDB + kg * 8]) =
                    *reinterpret_cast<const short8*>(d.Wt + (size_t)n * K + kc + kg * 8);
            }
            __syncthreads();
#pragma unroll
            for (int ks = 0; ks < 64; ks += 32) {
                short8 af[2], bfr[4];
#pragma unroll
                for (int rt = 0; rt < 2; ++rt)
                    af[rt] = *reinterpret_cast<const short8*>(
                        &As[(rb + rt * 16 + l16) * LDA + kc + ks + qd * 8]);
#pragma unroll
                for (int ct = 0; ct < 4; ++ct)
                    bfr[ct] = *reinterpret_cast<const short8*>(
                        &Bs[(cb + ct * 16 + l16) * LDB + ks + qd * 8]);
#pragma unroll
                for (int rt = 0; rt < 2; ++rt)
#pragma unroll
                    for (int ct = 0; ct < 4; ++ct)
                        acc[rt][ct] = __builtin_amdgcn_mfma_f32_16x16x32_bf16(
                            af[rt], bfr[ct], acc[rt][ct], 0, 0, 0);
            }
        }

        // epilogue: acc -> LDS tile -> paired u32 stores (16B/lane)
        __syncthreads();
        unsigned short* tile = Bs;
#pragma unroll
        for (int ct = 0; ct < 4; ++ct) {
            int col = cb + ct * 16 + l16;
            float bv = d.bias[col];
#pragma unroll
            for (int rt = 0; rt < 2; ++rt)
#pragma unroll
                for (int r = 0; r < 4; ++r)
                    tile[(rb + rt * 16 + qd * 4 + r) * TLD + col] = f2bf(acc[rt][ct][r] + bv);
        }
        __syncthreads();
#pragma unroll
        for (int rep = 0; rep < 4; ++rep) {
            int lrow = (tid >> 4) + rep * 16, seg = tid & 15;
            int gr = rbase + lrow;
            if (gr < M) {
                uint4 pk;
#pragma unroll
                for (int j = 0; j < 4; ++j) {
                    int pcol = seg * 4 + j;
                    unsigned lo16 = tile[lrow * TLD + pcol];
                    unsigned hi16 = tile[lrow * TLD + pcol + 64];
                    ((unsigned*)&pk)[j] = lo16 | (hi16 << 16);
                }
                *reinterpret_cast<uint4*>(&d.out[(size_t)gr * d.ldc + d.coloff + seg * 4]) = pk;
            }
        }
    }
}

// ================= edge GEMM: sequential A read, paired CSR-scatter write ==========
struct EdgePack {
    const float* A; const unsigned short* Wt; const float* bias;
    const int* pos; unsigned int* out; int M;
};

__global__ __launch_bounds__(256) void gemm_edge(EdgePack p0, EdgePack p1, int B0) {
    constexpr int K = 64, LDA = 72, LDB = 72, TLD = 133;
    __shared__ __align__(16) unsigned short As[64 * LDA];
    __shared__ __align__(16) unsigned short Bs[128 * LDB];

    EdgePack p; int blk;
    if ((int)blockIdx.x < B0) { p = p0; blk = blockIdx.x; } else { p = p1; blk = blockIdx.x - B0; }

    const int tid = threadIdx.x;
    const int rbase = blk * 64;

    for (int slot = tid; slot < 64 * 8; slot += 256) {
        int row = slot >> 3, kg = slot & 7;
        int gr = rbase + row;
        short8 s8 = {0, 0, 0, 0, 0, 0, 0, 0};
        if (gr < p.M) {
            const float* a = p.A + (size_t)gr * K + kg * 8;
            float4 f0 = *reinterpret_cast<const float4*>(a);
            float4 f1 = *reinterpret_cast<const float4*>(a + 4);
            s8[0] = (short)f2bf(f0.x); s8[1] = (short)f2bf(f0.y);
            s8[2] = (short)f2bf(f0.z); s8[3] = (short)f2bf(f0.w);
            s8[4] = (short)f2bf(f1.x); s8[5] = (short)f2bf(f1.y);
            s8[6] = (short)f2bf(f1.z); s8[7] = (short)f2bf(f1.w);
        }
        *reinterpret_cast<short8*>(&As[row * LDA + kg * 8]) = s8;
    }
    for (int slot = tid; slot < 128 * 8; slot += 256) {
        int n = slot >> 3, kg = slot & 7;
        *reinterpret_cast<short8*>(&Bs[n * LDB + kg * 8]) =
            *reinterpret_cast<const short8*>(p.Wt + (size_t)n * K + kg * 8);
    }
    __syncthreads();

    const int lane = tid & 63, w = tid >> 6;
    const int rb = (w >> 1) * 32, cb = (w & 1) * 64;
    const int qd = lane >> 4, l16 = lane & 15;

    f32x4 acc[2][4];
#pragma unroll
    for (int rt = 0; rt < 2; ++rt)
#pragma unroll
        for (int ct = 0; ct < 4; ++ct) { f32x4 z = {0.f,0.f,0.f,0.f}; acc[rt][ct] = z; }

#pragma unroll
    for (int ks = 0; ks < 64; ks += 32) {
        short8 af[2], bfr[4];
#pragma unroll
        for (int rt = 0; rt < 2; ++rt)
            af[rt] = *reinterpret_cast<const short8*>(&As[(rb + rt * 16 + l16) * LDA + ks + qd * 8]);
#pragma unroll
        for (int ct = 0; ct < 4; ++ct)
            bfr[ct] = *reinterpret_cast<const short8*>(&Bs[(cb + ct * 16 + l16) * LDB + ks + qd * 8]);
#pragma unroll
        for (int rt = 0; rt < 2; ++rt)
#pragma unroll
            for (int ct = 0; ct < 4; ++ct)
                acc[rt][ct] = __builtin_amdgcn_mfma_f32_16x16x32_bf16(
                    af[rt], bfr[ct], acc[rt][ct], 0, 0, 0);
    }

    __syncthreads();
    unsigned short* tile = Bs;
#pragma unroll
    for (int ct = 0; ct < 4; ++ct) {
        int col = cb + ct * 16 + l16;
        float bv = p.bias[col];
#pragma unroll
        for (int rt = 0; rt < 2; ++rt)
#pragma unroll
            for (int r = 0; r < 4; ++r)
                tile[(rb + rt * 16 + qd * 4 + r) * TLD + col] = f2bf(acc[rt][ct][r] + bv);
    }
    __syncthreads();
#pragma unroll
    for (int rep = 0; rep < 4; ++rep) {
        int lrow = (tid >> 4) + rep * 16, seg = tid & 15;
        int gr = rbase + lrow;
        if (gr < p.M) {
            int dpos = p.pos[gr];
            uint4 pk;
#pragma unroll
            for (int j = 0; j < 4; ++j) {
                int pcol = seg * 4 + j;
                unsigned lo16 = tile[lrow * TLD + pcol];
                unsigned hi16 = tile[lrow * TLD + pcol + 64];
                ((unsigned*)&pk)[j] = lo16 | (hi16 << 16);
            }
            *reinterpret_cast<uint4*>(&p.out[(size_t)dpos * 64 + seg * 4]) = pk;
        }
    }
}

// ===== output GEMM: out = LN( [agg|x] @ [Wo;Wnp] + bo + bnp ) with g,b ===========
// agg is bf16 paired-order; Wo rows permuted at prep time to match.
struct OutPack {
    const unsigned short* Aagg; const float* Ax;
    const unsigned short* Wt;   // [128][256]
    const float *bo, *bnp, *g, *bln; float* out; int M;
};

__global__ __launch_bounds__(256) void gemm_out_ln(OutPack p0, OutPack p1, int B0) {
    constexpr int K = 256, LDA = 264, LDB = 72, FTLD = 132;
    __shared__ __align__(16) char smemA[64 * LDA * 2];
    __shared__ __align__(16) unsigned short Bs[128 * LDB];
    unsigned short* As = (unsigned short*)smemA;

    OutPack p; int blk;
    if ((int)blockIdx.x < B0) { p = p0; blk = blockIdx.x; } else { p = p1; blk = blockIdx.x - B0; }

    const int tid = threadIdx.x;
    const int rbase = blk * 64;

    for (int slot = tid; slot < 64 * 32; slot += 256) {
        int row = slot >> 5, kg = slot & 31;
        int gr = rbase + row;
        short8 s8 = {0, 0, 0, 0, 0, 0, 0, 0};
        if (gr < p.M) {
            if (kg < 16) {
                s8 = *reinterpret_cast<const short8*>(p.Aagg + (size_t)gr * 128 + kg * 8);
            } else {
                const float* a = p.Ax + (size_t)gr * 128 + (kg - 16) * 8;
                float4 f0 = *reinterpret_cast<const float4*>(a);
                float4 f1 = *reinterpret_cast<const float4*>(a + 4);
                s8[0] = (short)f2bf(f0.x); s8[1] = (short)f2bf(f0.y);
                s8[2] = (short)f2bf(f0.z); s8[3] = (short)f2bf(f0.w);
                s8[4] = (short)f2bf(f1.x); s8[5] = (short)f2bf(f1.y);
                s8[6] = (short)f2bf(f1.z); s8[7] = (short)f2bf(f1.w);
            }
        }
        *reinterpret_cast<short8*>(&As[row * LDA + kg * 8]) = s8;
    }

    const int lane = tid & 63, w = tid >> 6;
    const int rb = (w >> 1) * 32, cb = (w & 1) * 64;
    const int qd = lane >> 4, l16 = lane & 15;

    f32x4 acc[2][4];
#pragma unroll
    for (int rt = 0; rt < 2; ++rt)
#pragma unroll
        for (int ct = 0; ct < 4; ++ct) { f32x4 z = {0.f,0.f,0.f,0.f}; acc[rt][ct] = z; }

    for (int kc = 0; kc < K; kc += 64) {
        __syncthreads();
        for (int slot = tid; slot < 128 * 8; slot += 256) {
            int n = slot >> 3, kg = slot & 7;
            *reinterpret_cast<short8*>(&Bs[n * LDB + kg * 8]) =
                *reinterpret_cast<const short8*>(p.Wt + (size_t)n * K + kc + kg * 8);
        }
        __syncthreads();
#pragma unroll
        for (int ks = 0; ks < 64; ks += 32) {
            short8 af[2], bfr[4];
#pragma unroll
            for (int rt = 0; rt < 2; ++rt)
                af[rt] = *reinterpret_cast<const short8*>(
                    &As[(rb + rt * 16 + l16) * LDA + kc + ks + qd * 8]);
#pragma unroll
            for (int ct = 0; ct < 4; ++ct)
                bfr[ct] = *reinterpret_cast<const short8*>(
                    &Bs[(cb + ct * 16 + l16) * LDB + ks + qd * 8]);
#pragma unroll
            for (int rt = 0; rt < 2; ++rt)
#pragma unroll
                for (int ct = 0; ct < 4; ++ct)
                    acc[rt][ct] = __builtin_amdgcn_mfma_f32_16x16x32_bf16(
                        af[rt], bfr[ct], acc[rt][ct], 0, 0, 0);
        }
    }

    __syncthreads();
    float* ftile = (float*)smemA;
#pragma unroll
    for (int ct = 0; ct < 4; ++ct) {
        int col = cb + ct * 16 + l16;
        float bv = p.bo[col] + p.bnp[col];
#pragma unroll
        for (int rt = 0; rt < 2; ++rt)
#pragma unroll
            for (int r = 0; r < 4; ++r)
                ftile[(rb + rt * 16 + qd * 4 + r) * FTLD + col] = acc[rt][ct][r] + bv;
    }
    __syncthreads();

    int r = tid >> 2, q4 = tid & 3;
    const float* rowp = &ftile[r * FTLD + q4 * 32];
    float s = 0.f, sq = 0.f;
#pragma unroll
    for (int j = 0; j < 8; ++j) {
        float4 v = *reinterpret_cast<const float4*>(rowp + j * 4);
        s += v.x + v.y + v.z + v.w;
        sq += v.x * v.x + v.y * v.y + v.z * v.z + v.w * v.w;
    }
    s += __shfl_xor(s, 1, 64);  s += __shfl_xor(s, 2, 64);
    sq += __shfl_xor(sq, 1, 64); sq += __shfl_xor(sq, 2, 64);
    float mu = s * (1.f / 128.f);
    float var = sq * (1.f / 128.f) - mu * mu;
    float rs = rsqrtf(var + 1e-5f);
    int gr = rbase + r;
    if (gr < p.M) {
#pragma unroll
        for (int j = 0; j < 8; ++j) {
            float4 v = *reinterpret_cast<const float4*>(rowp + j * 4);
            int c = q4 * 32 + j * 4;
            float4 gg = *reinterpret_cast<const float4*>(p.g + c);
            float4 bb = *reinterpret_cast<const float4*>(p.bln + c);
            float4 o;
            o.x = (v.x - mu) * rs * gg.x + bb.x;
            o.y = (v.y - mu) * rs * gg.y + bb.y;
            o.z = (v.z - mu) * rs * gg.z + bb.z;
            o.w = (v.w - mu) * rs * gg.w + bb.w;
            *reinterpret_cast<float4*>(&p.out[(size_t)gr * 128 + c]) = o;
        }
    }
}

// ================= CSR scan/scatter =================
__global__ __launch_bounds__(1024) void scan_partial(const int* c0, int N0, int* rp0, int* bs0, int B0,
                                                     const int* c1, int N1, int* rp1, int* bs1) {
    __shared__ int wsum[16];
    const int* c; int* rp; int* bs; int N; int blk;
    if ((int)blockIdx.x < B0) { c = c0; rp = rp0; bs = bs0; N = N0; blk = blockIdx.x; }
    else { c = c1; rp = rp1; bs = bs1; N = N1; blk = blockIdx.x - B0; }
    int tid = threadIdx.x, lane = tid & 63, w = tid >> 6;
    int i = blk * 1024 + tid;
    int v = (i < N) ? c[i] : 0;
    int s = v;
#pragma unroll
    for (int off = 1; off < 64; off <<= 1) {
        int t = __shfl_up(s, off, 64);
        if (lane >= off) s += t;
    }
    if (lane == 63) wsum[w] = s;
    __syncthreads();
    if (w == 0 && lane < 16) {
        int ws = wsum[lane];
#pragma unroll
        for (int off = 1; off < 16; off <<= 1) {
            int t = __shfl_up(ws, off, 64);
            if (lane >= off) ws += t;
        }
        wsum[lane] = ws;
    }
    __syncthreads();
    int wexcl = (w == 0) ? 0 : wsum[w - 1];
    if (i < N) rp[i] = wexcl + s - v;
    if (tid == 0) bs[blk] = wsum[15];
}

__global__ __launch_bounds__(128) void scan_mid(const int* bs0, int* off0, int B0, int* rpN0,
                                                const int* bs1, int* off1, int B1, int* rpN1) {
    int w = threadIdx.x >> 6, lane = threadIdx.x & 63;
    const int* bs = w ? bs1 : bs0;
    int* off = w ? off1 : off0;
    int B = w ? B1 : B0;
    int* rpN = w ? rpN1 : rpN0;
    int v = (lane < B) ? bs[lane] : 0;
    int s = v;
#pragma unroll
    for (int o = 1; o < 64; o <<= 1) {
        int t = __shfl_up(s, o, 64);
        if (lane >= o) s += t;
    }
    if (lane < B) off[lane] = s - v;
    int total = __shfl(s, B - 1, 64);
    if (lane == 0) *rpN = total;
}

__global__ __launch_bounds__(1024) void scan_add(int* rp0, int* cur0, const int* off0, int N0, int B0,
                                                 int* rp1, int* cur1, const int* off1, int N1) {
    int* rp; int* cur; const int* off; int N; int blk;
    if ((int)blockIdx.x < B0) { rp = rp0; cur = cur0; off = off0; N = N0; blk = blockIdx.x; }
    else { rp = rp1; cur = cur1; off = off1; N = N1; blk = blockIdx.x - B0; }
    int i = blk * 1024 + threadIdx.x;
    if (i < N) {
        int vv = rp[i] + off[blk];
        rp[i] = vv;
        cur[i] = vv;
    }
}

__global__ __launch_bounds__(256) void scatter_both(
    const int* __restrict__ s0, const int* __restrict__ d0, int E0, int* cur0, int* pos0, int* srcs0,
    const int* __restrict__ s1, const int* __restrict__ d1, int E1, int* cur1, int* pos1, int* srcs1) {
    int t = blockIdx.x * 256 + threadIdx.x;
    if (t < E0) {
        int p = atomicAdd(&cur0[d0[t]], 1);
        pos0[t] = p;
        srcs0[p] = s0[t];
    } else if (t < E0 + E1) {
        int tt = t - E0;
        int p = atomicAdd(&cur1[d1[tt]], 1);
        pos1[tt] = p;
        srcs1[p] = s1[tt];
    }
}

// ================= CSR gather attention: 1 wave/dst, paired cols, branchless ======
struct AttnPack {
    const unsigned int *q, *kv, *e;   // paired bf16x2 layouts
    const int *srcs;                  // padded with zeros past E
    const int *row_ptr;
    unsigned int* agg; int N;
};

__global__ __launch_bounds__(256) void attn_gather(AttnPack a0, AttnPack a1, int B0) {
    AttnPack a; int blk;
    if ((int)blockIdx.x < B0) { a = a0; blk = blockIdx.x; } else { a = a1; blk = blockIdx.x - B0; }
    int dst = blk * 4 + (threadIdx.x >> 6);
    if (dst >= a.N) return;
    int lane = threadIdx.x & 63;

    unsigned qp = a.q[(size_t)dst * 64 + lane];
    float qlo = bflo(qp), qhi = bfhi(qp);
    int beg = a.row_ptr[dst], end = a.row_ptr[dst + 1];
    float denl = 0.f, denh = 0.f, accl = 0.f, acch = 0.f;

    int sC = a.srcs[beg];   // padded: safe even when beg==end
    unsigned kC = a.kv[(size_t)sC * 128 + lane];
    unsigned vC = a.kv[(size_t)sC * 128 + 64 + lane];
    unsigned eC = a.e[(size_t)beg * 64 + lane];

    for (int i = beg; i < end; ++i) {
        int sN = a.srcs[i + 1];                       // always safe (pad)
        unsigned kN = a.kv[(size_t)sN * 128 + lane];
        unsigned vN = a.kv[(size_t)sN * 128 + 64 + lane];
        unsigned eN = a.e[(size_t)(i + 1) * 64 + lane];

        float kl = bflo(kC), kh = bfhi(kC);
        float vl = bflo(vC), vh = bfhi(vC);
        float el = bflo(eC), eh = bfhi(eC);
        float pl = qlo * (kl + el), ph = qhi * (kh + eh);
#pragma unroll
        for (int m = 1; m < 16; m <<= 1) {
            pl += __shfl_xor(pl, m, 64);
            ph += __shfl_xor(ph, m, 64);
        }
        float exl = __expf(pl * 0.25f), exh = __expf(ph * 0.25f);
        denl += exl; denh += exh;
        accl += exl * (vl + el);
        acch += exh * (vh + eh);
        kC = kN; vC = vN; eC = eN;
    }
    float ol = denl > 0.f ? accl / denl : 0.f;
    float oh = denh > 0.f ? acch / denh : 0.f;
    a.agg[(size_t)dst * 64 + lane] = (unsigned)f2bf(ol) | ((unsigned)f2bf(oh) << 16);
}

extern "C" void kernel_launch(void* const* d_in, const int* in_sizes, int n_in,
                              void* d_out, int out_size, void* d_ws, size_t ws_size,
                              hipStream_t stream) {
    const float* x_pc  = (const float*)d_in[0];
    const float* x_gr  = (const float*)d_in[1];
    const float* ea_pp = (const float*)d_in[2];
    const float* ea_pg = (const float*)d_in[3];
    const int* ei_pp   = (const int*)d_in[4];
    const int* ei_pg   = (const int*)d_in[5];
    const float *Wq_pp = (const float*)d_in[6],  *bq_pp = (const float*)d_in[7];
    const float *Wk_pp = (const float*)d_in[8],  *bk_pp = (const float*)d_in[9];
    const float *Wv_pp = (const float*)d_in[10], *bv_pp = (const float*)d_in[11];
    const float *We_pp = (const float*)d_in[12], *be_pp = (const float*)d_in[13];
    const float *Wo_pp = (const float*)d_in[14], *bo_pp = (const float*)d_in[15];
    const float *Wq_pg = (const float*)d_in[16], *bq_pg = (const float*)d_in[17];
    const float *Wk_pg = (const float*)d_in[18], *bk_pg = (const float*)d_in[19];
    const float *Wv_pg = (const float*)d_in[20], *bv_pg = (const float*)d_in[21];
    const float *We_pg = (const float*)d_in[22], *be_pg = (const float*)d_in[23];
    const float *Wo_pg = (const float*)d_in[24], *bo_pg = (const float*)d_in[25];
    const float *Wnp_pc = (const float*)d_in[26], *bnp_pc = (const float*)d_in[27];
    const float *g_pc   = (const float*)d_in[28], *bln_pc = (const float*)d_in[29];
    const float *Wnp_gr = (const float*)d_in[30], *bnp_gr = (const float*)d_in[31];
    const float *g_gr   = (const float*)d_in[32], *bln_gr = (const float*)d_in[33];

    const int N_pc = in_sizes[0] / 128;
    const int N_gr = in_sizes[1] / 128;
    const int E_pp = in_sizes[4] / 2;
    const int E_pg = in_sizes[5] / 2;

    char* ws = (char*)d_ws;
    size_t off = 0;
    auto alloc = [&](size_t bytes) -> char* {
        char* p = ws + off;
        off += (bytes + 255) & ~(size_t)255;
        return p;
    };
    unsigned short* Wt_q_pp = (unsigned short*)alloc(128 * 128 * 2);
    unsigned short* Wt_k_pp = (unsigned short*)alloc(128 * 128 * 2);
    unsigned short* Wt_v_pp = (unsigned short*)alloc(128 * 128 * 2);
    unsigned short* Wt_k_pg = (unsigned short*)alloc(128 * 128 * 2);
    unsigned short* Wt_v_pg = (unsigned short*)alloc(128 * 128 * 2);
    unsigned short* Wt_q_pg = (unsigned short*)alloc(128 * 128 * 2);
    unsigned short* Wt_e_pp = (unsigned short*)alloc(64 * 128 * 2);
    unsigned short* Wt_e_pg = (unsigned short*)alloc(64 * 128 * 2);
    unsigned short* Wt_cat_pp = (unsigned short*)alloc(256 * 128 * 2);
    unsigned short* Wt_cat_gr = (unsigned short*)alloc(256 * 128 * 2);

    unsigned int* q_pp  = (unsigned int*)alloc((size_t)N_pc * 64 * 4);
    unsigned int* kv_pp = (unsigned int*)alloc((size_t)N_pc * 128 * 4);
    unsigned int* q_pg  = (unsigned int*)alloc((size_t)N_gr * 64 * 4);
    unsigned int* kv_pg = (unsigned int*)alloc((size_t)N_pc * 128 * 4);
    unsigned int* e_pp  = (unsigned int*)alloc((size_t)(E_pp + 1) * 64 * 4);  // +1 pad row
    unsigned int* e_pg  = (unsigned int*)alloc((size_t)(E_pg + 1) * 64 * 4);
    unsigned int* agg_pp = (unsigned int*)alloc((size_t)N_pc * 64 * 4);
    unsigned int* agg_pg = (unsigned int*)alloc((size_t)N_gr * 64 * 4);
    int* row_ptr_pp = (int*)alloc((size_t)(N_pc + 1) * 4);
    int* cursor_pp  = (int*)alloc((size_t)N_pc * 4);
    int* pos_pp     = (int*)alloc((size_t)E_pp * 4);
    int* row_ptr_pg = (int*)alloc((size_t)(N_gr + 1) * 4);
    int* cursor_pg  = (int*)alloc((size_t)N_gr * 4);
    int* pos_pg     = (int*)alloc((size_t)E_pg * 4);
    int* bsum_pp    = (int*)alloc(64 * 4);
    int* boff_pp    = (int*)alloc(64 * 4);
    int* bsum_pg    = (int*)alloc(64 * 4);
    int* boff_pg    = (int*)alloc(64 * 4);
    char* zbase = ws + off;   // zero region: counts + padded srcs
    int* counts_pp = (int*)alloc((size_t)N_pc * 4);
    int* counts_pg = (int*)alloc((size_t)N_gr * 4);
    int* srcs_pp   = (int*)alloc((size_t)(E_pp + 8) * 4);  // pads stay zero
    int* srcs_pg   = (int*)alloc((size_t)(E_pg + 8) * 4);
    size_t zbytes = (size_t)((ws + off) - zbase);
    hipMemsetAsync(zbase, 0, zbytes, stream);

    float* out_pc = (float*)d_out;
    float* out_gr = out_pc + (size_t)N_pc * 128;

    const int* src_pp = ei_pp;
    const int* dst_pp = ei_pp + E_pp;
    const int* src_pg = ei_pg;
    const int* dst_pg = ei_pg + E_pg;

    // ---- weight prep + degree count (one launch) ----
    WPack wp;
    wp.w[0]  = {Wq_pp, Wt_q_pp, 128, 128, 0, 0};
    wp.w[1]  = {Wk_pp, Wt_k_pp, 128, 128, 0, 0};
    wp.w[2]  = {Wv_pp, Wt_v_pp, 128, 128, 0, 0};
    wp.w[3]  = {Wk_pg, Wt_k_pg, 128, 128, 0, 0};
    wp.w[4]  = {Wv_pg, Wt_v_pg, 128, 128, 0, 0};
    wp.w[5]  = {Wq_pg, Wt_q_pg, 128, 128, 0, 0};
    wp.w[6]  = {We_pp, Wt_e_pp, 64, 64, 0, 0};
    wp.w[7]  = {We_pg, Wt_e_pg, 64, 64, 0, 0};
    wp.w[8]  = {Wo_pp, Wt_cat_pp, 128, 256, 0, 1};    // paired-row perm (agg is paired)
    wp.w[9]  = {Wnp_pc, Wt_cat_pp, 128, 256, 128, 0};
    wp.w[10] = {Wo_pg, Wt_cat_gr, 128, 256, 0, 1};
    wp.w[11] = {Wnp_gr, Wt_cat_gr, 128, 256, 128, 0};
    const int NPREP = 48;
    const int gE = (E_pp + E_pg + 255) / 256;
    prep_and_count<<<NPREP + gE, 256, 0, stream>>>(wp, dst_pp, E_pp, counts_pp,
                                                   dst_pg, E_pg, counts_pg, NPREP);

    // ---- CSR build ----
    const int Bs_pp = (N_pc + 1023) / 1024, Bs_pg = (N_gr + 1023) / 1024;
    scan_partial<<<Bs_pp + Bs_pg, 1024, 0, stream>>>(counts_pp, N_pc, row_ptr_pp, bsum_pp, Bs_pp,
                                                     counts_pg, N_gr, row_ptr_pg, bsum_pg);
    scan_mid<<<1, 128, 0, stream>>>(bsum_pp, boff_pp, Bs_pp, &row_ptr_pp[N_pc],
                                    bsum_pg, boff_pg, Bs_pg, &row_ptr_pg[N_gr]);
    scan_add<<<Bs_pp + Bs_pg, 1024, 0, stream>>>(row_ptr_pp, cursor_pp, boff_pp, N_pc, Bs_pp,
                                                 row_ptr_pg, cursor_pg, boff_pg, N_gr);
    scatter_both<<<gE, 256, 0, stream>>>(src_pp, dst_pp, E_pp, cursor_pp, pos_pp, srcs_pp,
                                         src_pg, dst_pg, E_pg, cursor_pg, pos_pg, srcs_pg);

    // ---- node projections (both node types, one launch) ----
    NodePack np;
    np.d[0] = {Wt_q_pp, bq_pp, q_pp, 64, 0};
    np.d[1] = {Wt_k_pp, bk_pp, kv_pp, 128, 0};
    np.d[2] = {Wt_v_pp, bv_pp, kv_pp, 128, 64};
    np.d[3] = {Wt_k_pg, bk_pg, kv_pg, 128, 0};
    np.d[4] = {Wt_v_pg, bv_pg, kv_pg, 128, 64};
    np.nout = 5;
    NodePack ng{};
    ng.d[0] = {Wt_q_pg, bq_pg, q_pg, 64, 0};
    ng.nout = 1;
    int Bn0 = (N_pc + 63) / 64, Bn1 = (N_gr + 63) / 64;
    gemm_node<<<Bn0 + Bn1, 256, 0, stream>>>(x_pc, N_pc, np, Bn0, x_gr, N_gr, ng);

    // ---- edge projections: sequential read, paired CSR-scatter write ----
    EdgePack ep0 = {ea_pp, Wt_e_pp, be_pp, pos_pp, e_pp, E_pp};
    EdgePack ep1 = {ea_pg, Wt_e_pg, be_pg, pos_pg, e_pg, E_pg};
    int Be0 = (E_pp + 63) / 64, Be1 = (E_pg + 63) / 64;
    gemm_edge<<<Be0 + Be1, 256, 0, stream>>>(ep0, ep1, Be0);

    // ---- gather attention: 1 wave per dst ----
    AttnPack ap0 = {q_pp, kv_pp, e_pp, srcs_pp, row_ptr_pp, agg_pp, N_pc};
    AttnPack ap1 = {q_pg, kv_pg, e_pg, srcs_pg, row_ptr_pg, agg_pg, N_gr};
    int Ba0 = (N_pc + 3) / 4, Ba1 = (N_gr + 3) / 4;
    attn_gather<<<Ba0 + Ba1, 256, 0, stream>>>(ap0, ap1, Ba0);

    // ---- output GEMM + residual + LayerNorm ----
    OutPack op0 = {(const unsigned short*)agg_pp, x_pc, Wt_cat_pp, bo_pp, bnp_pc, g_pc, bln_pc, out_pc, N_pc};
    OutPack op1 = {(const unsigned short*)agg_pg, x_gr, Wt_cat_gr, bo_pg, bnp_gr, g_gr, bln_gr, out_gr, N_gr};
    int Bo0 = (N_pc + 63) / 64, Bo1 = (N_gr + 63) / 64;
    gemm_out_ln<<<Bo0 + Bo1, 256, 0, stream>>>(op0, op1, Bo0);
}